// Round 4
// baseline (434.361 us; speedup 1.0000x reference)
//
#include <hip/hip_runtime.h>
#include <hip/hip_cooperative_groups.h>
#include <stdint.h>

namespace cg = cooperative_groups;
typedef unsigned long long u64;

#define NMS_T 0.7f
#define MINSZ 16.0f
#define NPRE 6000
#define NPOST 300
#define CA   512       // matrix candidate count (NMS breaks at 300 kept ~ i=310)
#define CAPA 1024
#define CAP6 8192
#define NBIN 2048
#define GRID 512       // 2 blocks/CU co-resident: safe for cooperative launch
#define BLK  256

// ---- workspace layout (bytes) ----
#define OFF_CAND6  0                              // CAP6*8
#define OFF_CANDA  (OFF_CAND6 + CAP6*8)           // CAPA*8
#define OFF_ROIA   (OFF_CANDA + CAPA*8)           // CA*16
#define OFF_GMAT   (OFF_ROIA + CA*16)             // CA*8*8 (word-major: gmat[w*CA+r])
#define OFF_ORDER6 (OFF_GMAT + CA*64)             // NPRE*4 (fallback)
#define OFF_ROI6   (OFF_ORDER6 + NPRE*4)          // NPRE*16 (fallback)
#define OFF_H1     (OFF_ROI6 + NPRE*16)           // NBIN*4  -- zero region start
#define OFF_H2A    (OFF_H1 + NBIN*4)
#define OFF_H2B    (OFF_H2A + NBIN*4)
#define OFF_CNT    (OFF_H2B + NBIN*4)             // 16: [0]=cntA [1]=cnt6
#define OFF_VSUP   (OFF_CNT + 16)                 // 64: initial suppression bits (invalid)
#define OFF_ZEND   (OFF_VSUP + 64)                //     -- zero region end
#define OFF_KEYS   ((OFF_ZEND + 255) & ~255)      // n*4 key cache

__device__ __forceinline__ unsigned inv_key(float s) {
    unsigned u = __float_as_uint(s);
    unsigned k = (u & 0x80000000u) ? ~u : (u | 0x80000000u);
    return ~k;   // ascending inv == descending score
}

__device__ __forceinline__ float4 decode_box(const float4 a, const float4 l,
                                             float ih, float iw) {
    float h  = a.z - a.x;
    float w  = a.w - a.y;
    float cy = a.x + 0.5f * h;
    float cx = a.y + 0.5f * w;
    float ncy = l.x * h + cy;
    float ncx = l.y * w + cx;
    float nh  = expf(l.z) * h;
    float nw  = expf(l.w) * w;
    float y1 = fminf(fmaxf(ncy - 0.5f * nh, 0.0f), ih);
    float x1 = fminf(fmaxf(ncx - 0.5f * nw, 0.0f), iw);
    float y2 = fminf(fmaxf(ncy + 0.5f * nh, 0.0f), ih);
    float x2 = fminf(fmaxf(ncx + 0.5f * nw, 0.0f), iw);
    return make_float4(y1, x1, y2, x2);
}

__device__ __forceinline__ unsigned decode_inv(const float4 a, const float4 l,
                                               float ih, float iw, float sc) {
    float4 r = decode_box(a, l, ih, iw);
    bool v = ((r.z - r.x) >= MINSZ) && ((r.w - r.y) >= MINSZ);
    float s = v ? sc : -__builtin_inff();
    return inv_key(s);
}

// block-wide scan of a 2048-bin histogram; finds bins containing ranks t0 / t1.
__device__ void scan2048(const unsigned* __restrict__ h, unsigned t0, unsigned t1,
                         unsigned* psum, unsigned* res, int base) {
    int t = threadIdx.x;
    unsigned vals[8];
    unsigned s = 0;
#pragma unroll
    for (int j = 0; j < 8; j++) { vals[j] = h[t * 8 + j]; s += vals[j]; }
    psum[t] = s;
    __syncthreads();
    for (int off = 1; off < 256; off <<= 1) {
        unsigned v = (t >= off) ? psum[t - off] : 0u;
        __syncthreads();
        psum[t] += v;
        __syncthreads();
    }
    unsigned run = (t == 0) ? 0u : psum[t - 1];
#pragma unroll
    for (int j = 0; j < 8; j++) {
        unsigned c = vals[j];
        if (run < t0 && run + c >= t0) { res[base + 0] = t * 8 + j; res[base + 1] = run; }
        if (t1 && run < t1 && run + c >= t1) { res[base + 2] = t * 8 + j; res[base + 3] = run; }
        run += c;
    }
    __syncthreads();
}

struct SmHist { unsigned a[NBIN]; unsigned b[NBIN]; };
struct SmP5   { u64 k[CAPA]; };
struct SmP6   { float4 roi[CA]; float area[CA]; };
struct SmFb   { float y1[NPOST], x1[NPOST], y2[NPOST], x2[NPOST], ar[NPOST]; };
union Sm { SmHist h; SmP5 p5; SmP6 p6; SmFb fb; };

__global__ void __launch_bounds__(BLK) k_all(
        const float4* __restrict__ loc, const float* __restrict__ score,
        const float4* __restrict__ anchor, const int* __restrict__ ph,
        const int* __restrict__ pw, int n, char* __restrict__ ws,
        int has_cache, float* __restrict__ out) {
    cg::grid_group grid = cg::this_grid();
    __shared__ Sm sm;
    __shared__ unsigned psum[256];
    __shared__ unsigned res[16];
    __shared__ unsigned skept[NPOST];
    __shared__ int snk, sflag;

    const int tid = threadIdx.x, bid = blockIdx.x;
    const int gtid = bid * BLK + tid;
    const int gstride = GRID * BLK;

    u64*      cand6  = (u64*)(ws + OFF_CAND6);
    u64*      candA  = (u64*)(ws + OFF_CANDA);
    float4*   roiA   = (float4*)(ws + OFF_ROIA);
    u64*      gmat   = (u64*)(ws + OFF_GMAT);
    unsigned* order6 = (unsigned*)(ws + OFF_ORDER6);
    float4*   roi6   = (float4*)(ws + OFF_ROI6);
    unsigned* h1     = (unsigned*)(ws + OFF_H1);
    unsigned* h2a    = (unsigned*)(ws + OFF_H2A);
    unsigned* h2b    = (unsigned*)(ws + OFF_H2B);
    unsigned* cnts   = (unsigned*)(ws + OFF_CNT);
    u64*      vsup   = (u64*)(ws + OFF_VSUP);
    unsigned* cache  = (unsigned*)(ws + OFF_KEYS);

    const float ih = (float)ph[0], iw = (float)pw[0];

    // ---- P0: zero histograms/counters/vsup ----
    {
        unsigned* z = (unsigned*)(ws + OFF_H1);
        const int nz = (OFF_ZEND - OFF_H1) / 4;
        for (int i = gtid; i < nz; i += gstride) z[i] = 0;
    }
    grid.sync();

    // ---- P1: level-1 histogram (+ key cache) ----
    {
        unsigned* lh = sm.h.a;
        for (int b = tid; b < NBIN; b += BLK) lh[b] = 0;
        __syncthreads();
        for (int i = gtid; i < n; i += gstride) {
            unsigned inv = decode_inv(anchor[i], loc[i], ih, iw, score[i]);
            if (has_cache) cache[i] = inv;
            atomicAdd(&lh[inv >> 21], 1u);
        }
        __syncthreads();
        for (int b = tid; b < NBIN; b += BLK) {
            unsigned c = lh[b];
            if (c) atomicAdd(&h1[b], c);
        }
    }
    grid.sync();

    // ---- P2: level-2 histograms for targets CA and NPRE ----
    {
        scan2048(h1, CA, NPRE, psum, res, 0);      // res0=binA res2=bin6
        unsigned binA = res[0], bin6 = res[2];
        unsigned* lha = sm.h.a;
        unsigned* lhb = sm.h.b;
        for (int b = tid; b < NBIN; b += BLK) { lha[b] = 0; lhb[b] = 0; }
        __syncthreads();
        for (int i = gtid; i < n; i += gstride) {
            unsigned inv = has_cache ? cache[i] : decode_inv(anchor[i], loc[i], ih, iw, score[i]);
            unsigned top = inv >> 21;
            if (top == binA) atomicAdd(&lha[(inv >> 10) & (NBIN - 1)], 1u);
            if (top == bin6) atomicAdd(&lhb[(inv >> 10) & (NBIN - 1)], 1u);
        }
        __syncthreads();
        for (int b = tid; b < NBIN; b += BLK) {
            unsigned ca = lha[b], cb = lhb[b];
            if (ca) atomicAdd(&h2a[b], ca);
            if (cb) atomicAdd(&h2b[b], cb);
        }
    }
    grid.sync();

    // ---- P3: two-phase compaction (one atomic per counter per block) ----
    {
        scan2048(h1, CA, NPRE, psum, res, 0);          // res0 binA res1 runA res2 bin6 res3 run6
        scan2048(h2a, CA - res[1], 0, psum, res, 4);   // res4 subA
        scan2048(h2b, NPRE - res[3], 0, psum, res, 8); // res8 sub6
        unsigned THA = res[0] * (unsigned)NBIN + res[4];
        unsigned TH6 = res[2] * (unsigned)NBIN + res[8];
        unsigned c6 = 0, cA = 0;
        for (int i = gtid; i < n; i += gstride) {
            unsigned inv = has_cache ? cache[i] : decode_inv(anchor[i], loc[i], ih, iw, score[i]);
            unsigned pre = inv >> 10;
            c6 += (pre <= TH6);
            cA += (pre <= THA);
        }
        psum[tid] = (cA << 16) | c6;
        __syncthreads();
        for (int off = 1; off < 256; off <<= 1) {
            unsigned v = (tid >= off) ? psum[tid - off] : 0u;
            __syncthreads();
            psum[tid] += v;
            __syncthreads();
        }
        if (tid == 0) {
            unsigned tot = psum[255];
            res[12] = atomicAdd(&cnts[1], tot & 0xFFFFu);
            res[13] = atomicAdd(&cnts[0], tot >> 16);
        }
        __syncthreads();
        unsigned excl = (tid == 0) ? 0u : psum[tid - 1];
        unsigned pos6 = res[12] + (excl & 0xFFFFu);
        unsigned posA = res[13] + (excl >> 16);
        for (int i = gtid; i < n; i += gstride) {
            unsigned inv = has_cache ? cache[i] : decode_inv(anchor[i], loc[i], ih, iw, score[i]);
            unsigned pre = inv >> 10;
            if (pre <= TH6) {
                u64 key = ((u64)inv << 32) | (unsigned)i;
                if (pos6 < CAP6) cand6[pos6] = key;
                pos6++;
                if (pre <= THA) {
                    if (posA < CAPA) candA[posA] = key;
                    posA++;
                }
            }
        }
    }
    grid.sync();

    // ---- P5: rank top-CA candidates, decode into roiA[rank], mark invalid ----
    {
        unsigned MA = cnts[0]; if (MA > CAPA) MA = CAPA;
        unsigned cbase = (unsigned)bid * BLK;
        if (cbase < MA) {
            for (unsigned i = tid; i < MA; i += BLK) sm.p5.k[i] = candA[i];
            __syncthreads();
            unsigned c = cbase + tid;
            if (c < MA) {
                u64 key = sm.p5.k[c];
                int rank = 0;
#pragma unroll 8
                for (int j = 0; j < (int)MA; ++j) rank += (sm.p5.k[j] < key) ? 1 : 0;
                if (rank < CA) {
                    unsigned idx = (unsigned)key;
                    float4 b = decode_box(anchor[idx], loc[idx], ih, iw);
                    roiA[rank] = b;
                    if (!(((b.z - b.x) >= MINSZ) && ((b.w - b.y) >= MINSZ)))
                        atomicOr(&vsup[rank >> 6], 1ull << (rank & 63));
                }
            }
        }
    }
    grid.sync();

    // ---- P6: suppression bit-matrix (word-major), grid-wide ----
    {
        if (bid < (CA * 8) / BLK) {   // 16 blocks
            for (int i = tid; i < CA; i += BLK) {
                float4 b = roiA[i];
                sm.p6.roi[i] = b;
                sm.p6.area[i] = (b.z - b.x) * (b.w - b.y);
            }
            __syncthreads();
            int t6 = bid * BLK + tid;
            int row = t6 >> 3, w = t6 & 7;
            float4 b = sm.p6.roi[row];
            float ab = sm.p6.area[row];
            u64 bits = 0;
            int j0 = w * 64;
#pragma unroll 4
            for (int jj = 0; jj < 64; ++jj) {
                int j = j0 + jj;
                if (j > row) {
                    float4 c = sm.p6.roi[j];
                    float yy1 = fmaxf(b.x, c.x);
                    float xx1 = fmaxf(b.y, c.y);
                    float yy2 = fminf(b.z, c.z);
                    float xx2 = fminf(b.w, c.w);
                    float inter = fmaxf(yy2 - yy1, 0.0f) * fmaxf(xx2 - xx1, 0.0f);
                    float iou = inter / (ab + sm.p6.area[j] - inter);  // ref op order
                    if (iou > NMS_T) bits |= (1ULL << jj);
                }
            }
            gmat[w * CA + row] = bits;
        }
    }
    grid.sync();

    // ---- P7: block 0 — register/readlane serial scan, output, fallback ----
    if (bid != 0) return;
    {
        unsigned MA = cnts[0]; if (MA > CAPA) MA = CAPA;
        int Ceff = (int)((MA < (unsigned)CA) ? MA : (unsigned)CA);
        int nk = 0, flag = 0;
        if (tid < 64) {
            int j = tid;
            u64 sup[8];
#pragma unroll
            for (int w = 0; w < 8; ++w) sup[w] = vsup[w];
            bool done = false;
#pragma unroll
            for (int g = 0; g < 8; ++g) {
                if (!done) {
                    int base = g * 64;
                    if (base >= Ceff) { done = true; }
                    else {
                        u64 m[8];
#pragma unroll
                        for (int w = 0; w < 8; ++w) m[w] = gmat[w * CA + base + j];
                        u64 supg = sup[g];
                        for (int b = 0; b < 64; ++b) {
                            if (base + b >= Ceff) break;
                            if (!((supg >> b) & 1ULL)) {
                                if (j == 0) skept[nk] = (unsigned)(base + b);
                                ++nk;
                                if (nk == NPOST) { done = true; break; }
#pragma unroll
                                for (int w = 0; w < 8; ++w) {
                                    unsigned lo = (unsigned)__builtin_amdgcn_readlane((int)(unsigned)m[w], b);
                                    unsigned hi = (unsigned)__builtin_amdgcn_readlane((int)(unsigned)(m[w] >> 32), b);
                                    sup[w] |= ((u64)hi << 32) | (u64)lo;
                                }
                                supg = sup[g];
                            }
                        }
                    }
                }
            }
            flag = ((nk < NPOST && cnts[1] > (unsigned)Ceff) || cnts[0] > (unsigned)CAPA) ? 1 : 0;
        }
        if (tid == 0) { snk = nk; sflag = flag; }
        __syncthreads();
        nk = snk; flag = sflag;
        float4* out4 = (float4*)out;
        if (!flag) {
            for (int k = tid; k < NPOST; k += BLK) {
                float4 o = make_float4(0.f, 0.f, 0.f, 0.f);
                if (k < nk) o = roiA[skept[k]];
                out4[k] = o;
            }
            return;
        }
        // ---------- exact fallback (never taken on sane data) ----------
        unsigned M = cnts[1]; if (M > CAP6) M = CAP6;
        for (int r = tid; r < NPRE; r += BLK) order6[r] = 0xFFFFFFFFu;
        __syncthreads();
        for (unsigned c = tid; c < M; c += BLK) {
            u64 key = cand6[c];
            int rank = 0;
            for (unsigned jj = 0; jj < M; ++jj) rank += (cand6[jj] < key) ? 1 : 0;
            if (rank < NPRE) order6[rank] = (unsigned)key;
        }
        __syncthreads();
        for (int r = tid; r < NPRE; r += BLK) {
            unsigned idx = order6[r];
            float4 b = make_float4(0.f, 0.f, 0.f, 0.f);
            if (idx < (unsigned)n) b = decode_box(anchor[idx], loc[idx], ih, iw);
            roi6[r] = b;
        }
        __syncthreads();
        if (tid < 64) {
            int lane = tid;
            int nk2 = 0;
            for (int i = 0; i < NPRE; i++) {
                float4 b = roi6[i];
                float hs = b.z - b.x, wd = b.w - b.y;
                if (!(hs >= MINSZ && wd >= MINSZ)) continue;
                float ab = hs * wd;
                bool sup = false;
                for (int base = 0; base < nk2 && !sup; base += 64) {
                    int t = base + lane;
                    bool s = false;
                    if (t < nk2) {
                        float yy1 = fmaxf(b.x, sm.fb.y1[t]);
                        float xx1 = fmaxf(b.y, sm.fb.x1[t]);
                        float yy2 = fminf(b.z, sm.fb.y2[t]);
                        float xx2 = fminf(b.w, sm.fb.x2[t]);
                        float inter = fmaxf(yy2 - yy1, 0.0f) * fmaxf(xx2 - xx1, 0.0f);
                        float iou = inter / (sm.fb.ar[t] + ab - inter);
                        s = iou > NMS_T;
                    }
                    sup = (__ballot(s) != 0ULL);
                }
                if (!sup) {
                    if (lane == 0) {
                        sm.fb.y1[nk2] = b.x; sm.fb.x1[nk2] = b.y;
                        sm.fb.y2[nk2] = b.z; sm.fb.x2[nk2] = b.w; sm.fb.ar[nk2] = ab;
                    }
                    nk2++;
                    if (nk2 == NPOST) break;
                }
            }
            for (int k = lane; k < NPOST; k += 64) {
                float4 o = make_float4(0.f, 0.f, 0.f, 0.f);
                if (k < nk2) o = make_float4(sm.fb.y1[k], sm.fb.x1[k], sm.fb.y2[k], sm.fb.x2[k]);
                out4[k] = o;
            }
        }
    }
}

extern "C" void kernel_launch(void* const* d_in, const int* in_sizes, int n_in,
                              void* d_out, int out_size, void* d_ws, size_t ws_size,
                              hipStream_t stream) {
    const float4* loc    = (const float4*)d_in[0];
    const float*  score  = (const float*)d_in[1];
    const float4* anchor = (const float4*)d_in[2];
    const int*    ph     = (const int*)d_in[3];
    const int*    pw     = (const int*)d_in[4];
    int n = in_sizes[1];
    char* ws = (char*)d_ws;
    int has_cache = (ws_size >= (size_t)OFF_KEYS + (size_t)n * 4) ? 1 : 0;
    float* out = (float*)d_out;

    void* args[] = { (void*)&loc, (void*)&score, (void*)&anchor, (void*)&ph,
                     (void*)&pw, (void*)&n, (void*)&ws, (void*)&has_cache, (void*)&out };
    hipLaunchCooperativeKernel((const void*)k_all, dim3(GRID), dim3(BLK),
                               args, 0, stream);
}

// Round 5
// 210.619 us; speedup vs baseline: 2.0623x; 2.0623x over previous
//
#include <hip/hip_runtime.h>
#include <stdint.h>

typedef unsigned long long u64;

#define NMS_T 0.7f
#define MINSZ 16.0f
#define NPRE 6000
#define NPOST 300
#define CA   512       // matrix candidate count (NMS breaks at 300 kept ~ i=315)
#define CAPA 1024
#define CAP6 8192
#define NBIN 2048
#define BLKF 512

// ---- workspace layout (bytes) ----
#define OFF_CAND6  0                              // CAP6*8 = 65536
#define OFF_CANDA  (OFF_CAND6 + CAP6*8)           // CAPA*8 = 8192
#define OFF_ORDER6 (OFF_CANDA + CAPA*8)           // NPRE*4 (fallback)
#define OFF_ROI6   (OFF_ORDER6 + NPRE*4)          // NPRE*16 (fallback)
#define OFF_H1     (OFF_ROI6 + NPRE*16)           // NBIN*4  -- zero region start
#define OFF_H2A    (OFF_H1 + NBIN*4)
#define OFF_H2B    (OFF_H2A + NBIN*4)
#define OFF_CNT    (OFF_H2B + NBIN*4)             // 16: [0]=cntA [1]=cnt6
#define OFF_ZEND   (OFF_CNT + 16)                 //     -- zero region end
#define OFF_KEYS   ((OFF_ZEND + 255) & ~255)      // n*4 key cache

__device__ __forceinline__ unsigned inv_key(float s) {
    unsigned u = __float_as_uint(s);
    unsigned k = (u & 0x80000000u) ? ~u : (u | 0x80000000u);
    return ~k;   // ascending inv == descending score
}

__device__ __forceinline__ float4 decode_box(const float4 a, const float4 l,
                                             float ih, float iw) {
    float h  = a.z - a.x;
    float w  = a.w - a.y;
    float cy = a.x + 0.5f * h;
    float cx = a.y + 0.5f * w;
    float ncy = l.x * h + cy;
    float ncx = l.y * w + cx;
    float nh  = expf(l.z) * h;
    float nw  = expf(l.w) * w;
    float y1 = fminf(fmaxf(ncy - 0.5f * nh, 0.0f), ih);
    float x1 = fminf(fmaxf(ncx - 0.5f * nw, 0.0f), iw);
    float y2 = fminf(fmaxf(ncy + 0.5f * nh, 0.0f), ih);
    float x2 = fminf(fmaxf(ncx + 0.5f * nw, 0.0f), iw);
    return make_float4(y1, x1, y2, x2);
}

__device__ __forceinline__ unsigned decode_inv(const float4 a, const float4 l,
                                               float ih, float iw, float sc) {
    float4 r = decode_box(a, l, ih, iw);
    bool v = ((r.z - r.x) >= MINSZ) && ((r.w - r.y) >= MINSZ);
    float s = v ? sc : -__builtin_inff();
    return inv_key(s);
}

// block-wide (256 threads) scan of a 2048-bin histogram; finds bins with ranks t0/t1
__device__ void scan2048(const unsigned* __restrict__ h, unsigned t0, unsigned t1,
                         unsigned* psum, unsigned* res, int base) {
    int t = threadIdx.x;
    unsigned vals[8];
    unsigned s = 0;
#pragma unroll
    for (int j = 0; j < 8; j++) { vals[j] = h[t * 8 + j]; s += vals[j]; }
    psum[t] = s;
    __syncthreads();
    for (int off = 1; off < 256; off <<= 1) {
        unsigned v = (t >= off) ? psum[t - off] : 0u;
        __syncthreads();
        psum[t] += v;
        __syncthreads();
    }
    unsigned run = (t == 0) ? 0u : psum[t - 1];
#pragma unroll
    for (int j = 0; j < 8; j++) {
        unsigned c = vals[j];
        if (run < t0 && run + c >= t0) { res[base + 0] = t * 8 + j; res[base + 1] = run; }
        if (t1 && run < t1 && run + c >= t1) { res[base + 2] = t * 8 + j; res[base + 3] = run; }
        run += c;
    }
    __syncthreads();
}

__global__ void k_init(unsigned* __restrict__ zbase) {
    const int nz = (OFF_ZEND - OFF_H1) / 4;
    for (int i = blockIdx.x * blockDim.x + threadIdx.x; i < nz; i += gridDim.x * blockDim.x)
        zbase[i] = 0;
}

__global__ void __launch_bounds__(256) k_hist1(
        const float4* __restrict__ loc, const float* __restrict__ score,
        const float4* __restrict__ anchor, const int* __restrict__ ph,
        const int* __restrict__ pw, int n,
        unsigned* __restrict__ hist1, unsigned* __restrict__ cache, int has_cache) {
    __shared__ unsigned lh[NBIN];
    for (int b = threadIdx.x; b < NBIN; b += 256) lh[b] = 0;
    __syncthreads();
    float ih = (float)ph[0], iw = (float)pw[0];
    int stride = gridDim.x * 256;
    for (int i = blockIdx.x * 256 + threadIdx.x; i < n; i += stride) {
        unsigned inv = decode_inv(anchor[i], loc[i], ih, iw, score[i]);
        if (has_cache) cache[i] = inv;
        atomicAdd(&lh[inv >> 21], 1u);
    }
    __syncthreads();
    for (int b = threadIdx.x; b < NBIN; b += 256) {
        unsigned c = lh[b];
        if (c) atomicAdd(&hist1[b], c);
    }
}

__global__ void __launch_bounds__(256) k_hist2(
        const float4* __restrict__ loc, const float* __restrict__ score,
        const float4* __restrict__ anchor, const int* __restrict__ ph,
        const int* __restrict__ pw, int n, const unsigned* __restrict__ h1,
        unsigned* __restrict__ h2a, unsigned* __restrict__ h2b,
        const unsigned* __restrict__ cache, int has_cache) {
    __shared__ unsigned psum[256];
    __shared__ unsigned res[8];
    __shared__ unsigned lha[NBIN];
    __shared__ unsigned lhb[NBIN];
    scan2048(h1, CA, NPRE, psum, res, 0);
    for (int b = threadIdx.x; b < NBIN; b += 256) { lha[b] = 0; lhb[b] = 0; }
    __syncthreads();
    unsigned binA = res[0], bin6 = res[2];
    float ih = (float)ph[0], iw = (float)pw[0];
    int stride = gridDim.x * 256;
    for (int i = blockIdx.x * 256 + threadIdx.x; i < n; i += stride) {
        unsigned inv = has_cache ? cache[i] : decode_inv(anchor[i], loc[i], ih, iw, score[i]);
        unsigned top = inv >> 21;
        if (top == binA) atomicAdd(&lha[(inv >> 10) & (NBIN - 1)], 1u);
        if (top == bin6) atomicAdd(&lhb[(inv >> 10) & (NBIN - 1)], 1u);
    }
    __syncthreads();
    for (int b = threadIdx.x; b < NBIN; b += 256) {
        unsigned ca = lha[b], cb = lhb[b];
        if (ca) atomicAdd(&h2a[b], ca);
        if (cb) atomicAdd(&h2b[b], cb);
    }
}

// two-phase compaction: one atomicAdd per counter per block
__global__ void __launch_bounds__(256) k_compact(
        const float4* __restrict__ loc, const float* __restrict__ score,
        const float4* __restrict__ anchor, const int* __restrict__ ph,
        const int* __restrict__ pw, int n,
        const unsigned* __restrict__ h1, const unsigned* __restrict__ h2a,
        const unsigned* __restrict__ h2b,
        u64* __restrict__ candA, u64* __restrict__ cand6,
        unsigned* __restrict__ cnts, const unsigned* __restrict__ cache, int has_cache) {
    __shared__ unsigned psum[256];
    __shared__ unsigned res[16];
    int tid = threadIdx.x;
    scan2048(h1, CA, NPRE, psum, res, 0);          // res0 binA res1 runA res2 bin6 res3 run6
    scan2048(h2a, CA - res[1], 0, psum, res, 4);   // res4 subA
    scan2048(h2b, NPRE - res[3], 0, psum, res, 8); // res8 sub6
    unsigned THA = res[0] * (unsigned)NBIN + res[4];
    unsigned TH6 = res[2] * (unsigned)NBIN + res[8];
    float ih = (float)ph[0], iw = (float)pw[0];
    int stride = gridDim.x * 256;
    unsigned c6 = 0, cA = 0;
    for (int i = blockIdx.x * 256 + tid; i < n; i += stride) {
        unsigned inv = has_cache ? cache[i] : decode_inv(anchor[i], loc[i], ih, iw, score[i]);
        unsigned pre = inv >> 10;
        c6 += (pre <= TH6);
        cA += (pre <= THA);
    }
    psum[tid] = (cA << 16) | c6;
    __syncthreads();
    for (int off = 1; off < 256; off <<= 1) {
        unsigned v = (tid >= off) ? psum[tid - off] : 0u;
        __syncthreads();
        psum[tid] += v;
        __syncthreads();
    }
    if (tid == 0) {
        unsigned tot = psum[255];
        res[12] = atomicAdd(&cnts[1], tot & 0xFFFFu);
        res[13] = atomicAdd(&cnts[0], tot >> 16);
    }
    __syncthreads();
    unsigned excl = (tid == 0) ? 0u : psum[tid - 1];
    unsigned pos6 = res[12] + (excl & 0xFFFFu);
    unsigned posA = res[13] + (excl >> 16);
    for (int i = blockIdx.x * 256 + tid; i < n; i += stride) {
        unsigned inv = has_cache ? cache[i] : decode_inv(anchor[i], loc[i], ih, iw, score[i]);
        unsigned pre = inv >> 10;
        if (pre <= TH6) {
            u64 key = ((u64)inv << 32) | (unsigned)i;
            if (pos6 < CAP6) cand6[pos6] = key;
            pos6++;
            if (pre <= THA) {
                if (posA < CAPA) candA[posA] = key;
                posA++;
            }
        }
    }
}

struct SmMain {
    u64    keys[CAPA];      // 8 KB
    float4 roi[CA];         // 8 KB
    float  area[CA];        // 2 KB
    u64    mat[8 * CA];     // 32 KB, word-major: mat[w*CA+row]
};
struct SmFb {
    u64   lk[CAP6];         // 64 KB
    float y1[NPOST], x1[NPOST], y2[NPOST], x2[NPOST], ar[NPOST];
};
union SmF { SmMain m; SmFb fb; };

// single-block finisher: rank -> decode -> bit-matrix -> register scan -> output (+fallback)
__global__ void __launch_bounds__(BLKF) k_final(
        const float4* __restrict__ loc, const float* __restrict__ score,
        const float4* __restrict__ anchor, const int* __restrict__ ph,
        const int* __restrict__ pw, int n,
        const u64* __restrict__ candA, const u64* __restrict__ cand6,
        const unsigned* __restrict__ cnts,
        unsigned* __restrict__ order6, float4* __restrict__ roi6,
        float* __restrict__ out) {
    __shared__ SmF sm;
    __shared__ unsigned skept[NPOST];
    __shared__ unsigned svsup[CA / 32];
    __shared__ int snk, sflag;
    int tid = threadIdx.x;
    float ih = (float)ph[0], iw = (float)pw[0];
    unsigned cntA = cnts[0], cnt6 = cnts[1];
    unsigned MA = cntA < (unsigned)CAPA ? cntA : (unsigned)CAPA;

    // ---- A: load keys, zero roi/area/vsup ----
    for (int r = tid; r < CA; r += BLKF) { sm.m.roi[r] = make_float4(0.f,0.f,0.f,0.f); sm.m.area[r] = 0.f; }
    if (tid < CA / 32) svsup[tid] = 0;
    for (unsigned i = tid; i < MA; i += BLKF) sm.m.keys[i] = candA[i];
    __syncthreads();
    // ---- B: exact rank (keys unique: index embedded), decode into roi[rank] ----
    for (unsigned c = tid; c < MA; c += BLKF) {
        u64 key = sm.m.keys[c];
        int rank = 0;
#pragma unroll 8
        for (unsigned j = 0; j < MA; ++j) rank += (sm.m.keys[j] < key) ? 1 : 0;
        if (rank < CA) {
            unsigned idx = (unsigned)key;
            float4 b = decode_box(anchor[idx], loc[idx], ih, iw);
            sm.m.roi[rank] = b;
            sm.m.area[rank] = (b.z - b.x) * (b.w - b.y);
            if (!(((b.z - b.x) >= MINSZ) && ((b.w - b.y) >= MINSZ)))
                atomicOr(&svsup[rank >> 5], 1u << (rank & 31));
        }
    }
    __syncthreads();
    // ---- C: suppression bit-matrix (triangular skip; zeroed rows give NaN -> no bits) ----
    for (int task = tid; task < CA * 8; task += BLKF) {
        int w = task >> 9;            // task / CA
        int row = task & (CA - 1);
        u64 bits = 0;
        int j0 = w << 6;
        if (j0 + 63 > row) {
            float4 b = sm.m.roi[row];
            float ab = sm.m.area[row];
#pragma unroll 4
            for (int jj = 0; jj < 64; ++jj) {
                int j = j0 + jj;
                if (j > row) {
                    float4 c = sm.m.roi[j];
                    float yy1 = fmaxf(b.x, c.x);
                    float xx1 = fmaxf(b.y, c.y);
                    float yy2 = fminf(b.z, c.z);
                    float xx2 = fminf(b.w, c.w);
                    float inter = fmaxf(yy2 - yy1, 0.0f) * fmaxf(xx2 - xx1, 0.0f);
                    float iou = inter / (ab + sm.m.area[j] - inter);  // ref op order
                    if (iou > NMS_T) bits |= (1ULL << jj);
                }
            }
        }
        sm.m.mat[w * CA + row] = bits;
    }
    __syncthreads();
    // ---- D: register/readlane serial scan (wave 0), break at 300 kept ----
    int Ceff = (int)(MA < (unsigned)CA ? MA : (unsigned)CA);
    if (tid < 64) {
        int j = tid;
        u64 sup[8];
#pragma unroll
        for (int w = 0; w < 8; ++w) sup[w] = ((u64)svsup[2 * w + 1] << 32) | (u64)svsup[2 * w];
        int nk = 0;
        bool done = false;
#pragma unroll
        for (int g = 0; g < 8; ++g) {
            if (!done) {
                int base = g * 64;
                if (base >= Ceff) { done = true; }
                else {
                    u64 m[8];
#pragma unroll
                    for (int w = 0; w < 8; ++w) m[w] = sm.m.mat[w * CA + base + j];
                    u64 supg = sup[g];
                    for (int b = 0; b < 64; ++b) {
                        if (base + b >= Ceff) break;
                        if (!((supg >> b) & 1ULL)) {
                            if (j == 0) skept[nk] = (unsigned)(base + b);
                            ++nk;
                            if (nk == NPOST) { done = true; break; }
#pragma unroll
                            for (int w = 0; w < 8; ++w) {
                                unsigned lo = (unsigned)__builtin_amdgcn_readlane((int)(unsigned)m[w], b);
                                unsigned hi = (unsigned)__builtin_amdgcn_readlane((int)(unsigned)(m[w] >> 32), b);
                                sup[w] |= ((u64)hi << 32) | (u64)lo;
                            }
                            supg = sup[g];
                        }
                    }
                }
            }
        }
        if (j == 0) {
            snk = nk;
            sflag = ((nk < NPOST && cnt6 > (unsigned)Ceff) || cntA > (unsigned)CAPA) ? 1 : 0;
        }
    }
    __syncthreads();
    int nk = snk, flag = sflag;
    float4* out4 = (float4*)out;
    if (!flag) {
        for (int k = tid; k < NPOST; k += BLKF) {
            float4 o = make_float4(0.f, 0.f, 0.f, 0.f);
            if (k < nk) o = sm.m.roi[skept[k]];
            out4[k] = o;
        }
        return;
    }
    __syncthreads();
    // ---------- exact fallback (flag-gated; never taken on sane data) ----------
    unsigned M = cnt6 < (unsigned)CAP6 ? cnt6 : (unsigned)CAP6;
    for (unsigned i = tid; i < CAP6; i += BLKF) sm.fb.lk[i] = (i < M) ? cand6[i] : ~0ULL;
    for (int r = tid; r < NPRE; r += BLKF) order6[r] = 0xFFFFFFFFu;
    __syncthreads();
    for (unsigned c = tid; c < M; c += BLKF) {
        u64 key = sm.fb.lk[c];
        int rank = 0;
        for (unsigned jj = 0; jj < M; ++jj) rank += (sm.fb.lk[jj] < key) ? 1 : 0;
        if (rank < NPRE) order6[rank] = (unsigned)key;
    }
    __syncthreads();
    for (int r = tid; r < NPRE; r += BLKF) {
        unsigned idx = order6[r];
        float4 b = make_float4(0.f, 0.f, 0.f, 0.f);
        if (idx < (unsigned)n) b = decode_box(anchor[idx], loc[idx], ih, iw);
        roi6[r] = b;
    }
    __syncthreads();
    if (tid < 64) {
        int lane = tid;
        int nk2 = 0;
        for (int i = 0; i < NPRE; i++) {
            float4 b = roi6[i];
            float hs = b.z - b.x, wd = b.w - b.y;
            if (!(hs >= MINSZ && wd >= MINSZ)) continue;
            float ab = hs * wd;
            bool sup = false;
            for (int base = 0; base < nk2 && !sup; base += 64) {
                int t = base + lane;
                bool s = false;
                if (t < nk2) {
                    float yy1 = fmaxf(b.x, sm.fb.y1[t]);
                    float xx1 = fmaxf(b.y, sm.fb.x1[t]);
                    float yy2 = fminf(b.z, sm.fb.y2[t]);
                    float xx2 = fminf(b.w, sm.fb.x2[t]);
                    float inter = fmaxf(yy2 - yy1, 0.0f) * fmaxf(xx2 - xx1, 0.0f);
                    float iou = inter / (sm.fb.ar[t] + ab - inter);
                    s = iou > NMS_T;
                }
                sup = (__ballot(s) != 0ULL);
            }
            if (!sup) {
                if (lane == 0) {
                    sm.fb.y1[nk2] = b.x; sm.fb.x1[nk2] = b.y;
                    sm.fb.y2[nk2] = b.z; sm.fb.x2[nk2] = b.w; sm.fb.ar[nk2] = ab;
                }
                nk2++;
                if (nk2 == NPOST) break;
            }
        }
        for (int k = lane; k < NPOST; k += 64) {
            float4 o = make_float4(0.f, 0.f, 0.f, 0.f);
            if (k < nk2) o = make_float4(sm.fb.y1[k], sm.fb.x1[k], sm.fb.y2[k], sm.fb.x2[k]);
            out4[k] = o;
        }
    }
}

extern "C" void kernel_launch(void* const* d_in, const int* in_sizes, int n_in,
                              void* d_out, int out_size, void* d_ws, size_t ws_size,
                              hipStream_t stream) {
    const float4* loc    = (const float4*)d_in[0];
    const float*  score  = (const float*)d_in[1];
    const float4* anchor = (const float4*)d_in[2];
    const int*    ph     = (const int*)d_in[3];
    const int*    pw     = (const int*)d_in[4];
    int n = in_sizes[1];

    char* ws = (char*)d_ws;
    u64*      cand6  = (u64*)(ws + OFF_CAND6);
    u64*      candA  = (u64*)(ws + OFF_CANDA);
    unsigned* order6 = (unsigned*)(ws + OFF_ORDER6);
    float4*   roi6   = (float4*)(ws + OFF_ROI6);
    unsigned* h1     = (unsigned*)(ws + OFF_H1);
    unsigned* h2a    = (unsigned*)(ws + OFF_H2A);
    unsigned* h2b    = (unsigned*)(ws + OFF_H2B);
    unsigned* cnts   = (unsigned*)(ws + OFF_CNT);
    unsigned* cache  = (unsigned*)(ws + OFF_KEYS);
    int has_cache = (ws_size >= (size_t)OFF_KEYS + (size_t)n * 4) ? 1 : 0;
    float* out = (float*)d_out;

    k_init    <<<dim3(8),    dim3(256), 0, stream>>>(h1);
    k_hist1   <<<dim3(1024), dim3(256), 0, stream>>>(loc, score, anchor, ph, pw, n, h1, cache, has_cache);
    k_hist2   <<<dim3(256),  dim3(256), 0, stream>>>(loc, score, anchor, ph, pw, n, h1, h2a, h2b, cache, has_cache);
    k_compact <<<dim3(256),  dim3(256), 0, stream>>>(loc, score, anchor, ph, pw, n, h1, h2a, h2b,
                                                     candA, cand6, cnts, cache, has_cache);
    k_final   <<<dim3(1),    dim3(BLKF), 0, stream>>>(loc, score, anchor, ph, pw, n,
                                                      candA, cand6, cnts, order6, roi6, out);
}

// Round 6
// 134.418 us; speedup vs baseline: 3.2314x; 1.5669x over previous
//
#include <hip/hip_runtime.h>
#include <stdint.h>

typedef unsigned long long u64;

#define NMS_T 0.7f
#define MINSZ 16.0f
#define NPRE 6000
#define NPOST 300
#define CA   512
#define CAPA 2048
#define CAP6 8192
#define NBIN 2048

// ---- workspace layout (bytes) ----
#define OFF_CAND6  0                         // CAP6*8  = 65536
#define OFF_CANDA  (OFF_CAND6 + CAP6*8)      // CAPA*8  = 16384
#define OFF_ROIA   (OFF_CANDA + CAPA*8)      // CA*16   = 8192
#define OFF_VSUP   (OFF_ROIA + CA*16)        // 64
#define OFF_ORDER6 (OFF_VSUP + 64)           // NPRE*4  (fallback)
#define OFF_ROI6   (OFF_ORDER6 + NPRE*4)     // NPRE*16 (fallback)
#define OFF_GMAT   (OFF_ROI6 + NPRE*16)      // CA*8*8 word-major gmat[w*CA+row]
#define OFF_H      (OFF_GMAT + CA*64)        // NBIN*4  -- zero region start
#define OFF_CNT    (OFF_H + NBIN*4)          // 32: [0]=cntA [1]=cnt6
#define ZERO_BYTES (NBIN*4 + 32)

__device__ __forceinline__ unsigned inv_key(float s) {
    unsigned u = __float_as_uint(s);
    unsigned k = (u & 0x80000000u) ? ~u : (u | 0x80000000u);
    return ~k;   // ascending inv == descending score
}

__device__ __forceinline__ float4 decode_box(const float4 a, const float4 l,
                                             float ih, float iw) {
    float h  = a.z - a.x;
    float w  = a.w - a.y;
    float cy = a.x + 0.5f * h;
    float cx = a.y + 0.5f * w;
    float ncy = l.x * h + cy;
    float ncx = l.y * w + cx;
    float nh  = expf(l.z) * h;
    float nw  = expf(l.w) * w;
    float y1 = fminf(fmaxf(ncy - 0.5f * nh, 0.0f), ih);
    float x1 = fminf(fmaxf(ncx - 0.5f * nw, 0.0f), iw);
    float y2 = fminf(fmaxf(ncy + 0.5f * nh, 0.0f), ih);
    float x2 = fminf(fmaxf(ncx + 0.5f * nw, 0.0f), iw);
    return make_float4(y1, x1, y2, x2);
}

__device__ __forceinline__ int sbin_of(float s) {
    int b = (int)(s * 2048.0f);
    b = b < 0 ? 0 : (b > 2047 ? 2047 : b);
    return 2047 - b;           // ascending = descending score
}

// block-wide (256 threads) scan of 2048-bin histogram; bins containing ranks t0/t1
__device__ void scan2048(const unsigned* __restrict__ h, unsigned t0, unsigned t1,
                         unsigned* psum, unsigned* res, int base) {
    int t = threadIdx.x;
    unsigned vals[8];
    unsigned s = 0;
#pragma unroll
    for (int j = 0; j < 8; j++) { vals[j] = h[t * 8 + j]; s += vals[j]; }
    psum[t] = s;
    __syncthreads();
    for (int off = 1; off < 256; off <<= 1) {
        unsigned v = (t >= off) ? psum[t - off] : 0u;
        __syncthreads();
        psum[t] += v;
        __syncthreads();
    }
    unsigned run = (t == 0) ? 0u : psum[t - 1];
#pragma unroll
    for (int j = 0; j < 8; j++) {
        unsigned c = vals[j];
        if (run < t0 && run + c >= t0) { res[base + 0] = t * 8 + j; res[base + 1] = run; }
        if (t1 && run < t1 && run + c >= t1) { res[base + 2] = t * 8 + j; res[base + 3] = run; }
        run += c;
    }
    __syncthreads();
}

// ---- 1: score-only histogram (4 MB read) ----
__global__ void __launch_bounds__(256) k_hist(const float* __restrict__ score, int n,
                                              unsigned* __restrict__ h) {
    __shared__ unsigned lh[NBIN];
    for (int b = threadIdx.x; b < NBIN; b += 256) lh[b] = 0;
    __syncthreads();
    int gtid = blockIdx.x * 256 + threadIdx.x;
    int stride = gridDim.x * 256;
    int n4 = n >> 2;
    const float4* s4 = (const float4*)score;
    for (int i = gtid; i < n4; i += stride) {
        float4 s = s4[i];
        atomicAdd(&lh[sbin_of(s.x)], 1u);
        atomicAdd(&lh[sbin_of(s.y)], 1u);
        atomicAdd(&lh[sbin_of(s.z)], 1u);
        atomicAdd(&lh[sbin_of(s.w)], 1u);
    }
    for (int i = n4 * 4 + gtid; i < n; i += stride) atomicAdd(&lh[sbin_of(score[i])], 1u);
    __syncthreads();
    for (int b = threadIdx.x; b < NBIN; b += 256) {
        unsigned c = lh[b];
        if (c) atomicAdd(&h[b], c);
    }
}

// ---- 2: threshold + two-phase compaction; decode only selected (~6.5K) ----
__global__ void __launch_bounds__(256) k_compact(
        const float4* __restrict__ loc, const float* __restrict__ score,
        const float4* __restrict__ anchor, const int* __restrict__ ph,
        const int* __restrict__ pw, int n, const unsigned* __restrict__ h,
        u64* __restrict__ candA, u64* __restrict__ cand6, unsigned* __restrict__ cnts) {
    __shared__ unsigned psum[256];
    __shared__ unsigned res[8];
    __shared__ unsigned sbase[2];
    int tid = threadIdx.x;
    scan2048(h, CA, NPRE, psum, res, 0);      // res0 = bA, res2 = b6
    unsigned bA = res[0], b6 = res[2];
    float ih = (float)ph[0], iw = (float)pw[0];
    int gtid = blockIdx.x * 256 + tid;
    int stride = gridDim.x * 256;
    // phase 1: count
    unsigned cA = 0, c6 = 0;
    for (int i = gtid; i < n; i += stride) {
        unsigned hb = (unsigned)sbin_of(score[i]);
        c6 += (hb <= b6);
        cA += (hb <= bA);
    }
    psum[tid] = (cA << 16) | c6;
    __syncthreads();
    for (int off = 1; off < 256; off <<= 1) {
        unsigned v = (tid >= off) ? psum[tid - off] : 0u;
        __syncthreads();
        psum[tid] += v;
        __syncthreads();
    }
    if (tid == 0) {
        unsigned tot = psum[255];
        sbase[0] = atomicAdd(&cnts[1], tot & 0xFFFFu);
        sbase[1] = atomicAdd(&cnts[0], tot >> 16);
    }
    __syncthreads();
    unsigned excl = (tid == 0) ? 0u : psum[tid - 1];
    unsigned pos6 = sbase[0] + (excl & 0xFFFFu);
    unsigned posA = sbase[1] + (excl >> 16);
    // phase 2: decode selected, write exact keys
    for (int i = gtid; i < n; i += stride) {
        float s = score[i];
        unsigned hb = (unsigned)sbin_of(s);
        if (hb <= b6) {
            float4 r = decode_box(anchor[i], loc[i], ih, iw);
            bool valid = ((r.z - r.x) >= MINSZ) && ((r.w - r.y) >= MINSZ);
            float ms = valid ? s : -__builtin_inff();
            u64 key = ((u64)inv_key(ms) << 32) | (unsigned)i;
            if (pos6 < CAP6) cand6[pos6] = key;
            pos6++;
            if (hb <= bA) {
                if (posA < CAPA) candA[posA] = key;
                posA++;
            }
        }
    }
}

// register-blocked exact rank + decode of top-CA
template <int KB>
__device__ __forceinline__ void rank_block(const u64* lk2, unsigned MP,
                                           const float4* anchor, const float4* loc,
                                           float ih, float iw,
                                           float4* sroi, float* sarea, unsigned* svalid) {
    u64 kc[KB]; int rr[KB];
#pragma unroll
    for (int k = 0; k < KB; ++k) {
        unsigned c = threadIdx.x + k * 256u;
        kc[k] = (c < MP) ? lk2[c] : ~0ULL;
        rr[k] = 0;
    }
    for (unsigned j = 0; j < MP; ++j) {
        u64 kj = lk2[j];
#pragma unroll
        for (int k = 0; k < KB; ++k) rr[k] += (kj < kc[k]) ? 1 : 0;
    }
#pragma unroll
    for (int k = 0; k < KB; ++k) {
        unsigned c = threadIdx.x + k * 256u;
        if (c < MP && rr[k] < CA) {
            unsigned idx = (unsigned)kc[k];
            float4 b = decode_box(anchor[idx], loc[idx], ih, iw);
            sroi[rr[k]] = b;
            sarea[rr[k]] = (b.z - b.x) * (b.w - b.y);
            if (((b.z - b.x) >= MINSZ) && ((b.w - b.y) >= MINSZ))
                atomicOr(&svalid[rr[k] >> 5], 1u << (rr[k] & 31));
        }
    }
}

// ---- 3: 8 parallel blocks: prune -> rank -> decode -> matrix slice ----
__global__ void __launch_bounds__(256) k_rankmat(
        const float4* __restrict__ loc, const float4* __restrict__ anchor,
        const int* __restrict__ ph, const int* __restrict__ pw,
        const u64* __restrict__ candA, const unsigned* __restrict__ cnts,
        u64* __restrict__ gmat, float4* __restrict__ roiA, u64* __restrict__ vsup_g) {
    __shared__ u64 lk[CAPA];
    __shared__ u64 lk2[CAPA];
    __shared__ unsigned shist[NBIN];
    __shared__ float4 sroi[CA];
    __shared__ float sarea[CA];
    __shared__ unsigned svalid[CA / 32];
    __shared__ unsigned psum[256];
    __shared__ unsigned res2[8];
    __shared__ unsigned sInvLo, sMP;
    int tid = threadIdx.x;
    unsigned cntA = cnts[0];
    if (cntA > CAPA) return;                      // flag path handled in k_scan
    unsigned MA = cntA;
    float ih = (float)ph[0], iw = (float)pw[0];

    if (tid == 0) { sInvLo = 0xFFFFFFFFu; sMP = 0; res2[0] = NBIN - 1; }
    for (int b = tid; b < NBIN; b += 256) shist[b] = 0;
    for (int r = tid; r < CA; r += 256) { sroi[r] = make_float4(0.f,0.f,0.f,0.f); sarea[r] = 0.f; }
    if (tid < CA / 32) svalid[tid] = 0;
    __syncthreads();
    for (unsigned i = tid; i < MA; i += 256) {
        u64 k = candA[i];
        lk[i] = k;
        atomicMin(&sInvLo, (unsigned)(k >> 32));
    }
    __syncthreads();
    unsigned invLo = sInvLo;
    for (unsigned i = tid; i < MA; i += 256) {
        unsigned d = ((unsigned)(lk[i] >> 32) - invLo) >> 3;
        atomicAdd(&shist[d > 2047u ? 2047u : d], 1u);
    }
    __syncthreads();
    scan2048(shist, CA, 0, psum, res2, 0);        // res2[0] = sub-bin threshold
    unsigned sbT = res2[0];
    for (unsigned i = tid; i < MA; i += 256) {
        unsigned d = ((unsigned)(lk[i] >> 32) - invLo) >> 3;
        if ((d > 2047u ? 2047u : d) <= sbT) lk2[atomicAdd(&sMP, 1u)] = lk[i];
    }
    __syncthreads();
    unsigned MP = sMP;                             // >= min(512, MA), typically ~520
    if (MP <= 1024) rank_block<4>(lk2, MP, anchor, loc, ih, iw, sroi, sarea, svalid);
    else            rank_block<8>(lk2, MP, anchor, loc, ih, iw, sroi, sarea, svalid);
    __syncthreads();
    // matrix slice: this block owns word-column w = blockIdx.x
    int w = blockIdx.x;
    int j0 = w * 64;
#pragma unroll
    for (int rrr = 0; rrr < 2; ++rrr) {
        int row = tid + rrr * 256;
        u64 bits = 0;
        if (j0 + 63 > row) {
            float4 b = sroi[row];
            float ab = sarea[row];
#pragma unroll 4
            for (int jj = 0; jj < 64; ++jj) {
                int j = j0 + jj;
                if (j > row) {
                    float4 c = sroi[j];
                    float yy1 = fmaxf(b.x, c.x);
                    float xx1 = fmaxf(b.y, c.y);
                    float yy2 = fminf(b.z, c.z);
                    float xx2 = fminf(b.w, c.w);
                    float inter = fmaxf(yy2 - yy1, 0.0f) * fmaxf(xx2 - xx1, 0.0f);
                    float iou = inter / (ab + sarea[j] - inter);  // ref op order
                    if (iou > NMS_T) bits |= (1ULL << jj);
                }
            }
        }
        gmat[w * CA + row] = bits;
    }
    if (blockIdx.x == 0) {
        for (int r = tid; r < CA; r += 256) roiA[r] = sroi[r];
        if (tid < 8) vsup_g[tid] = ((u64)svalid[2 * tid + 1] << 32) | (u64)svalid[2 * tid];
    }
}

struct SmFb {
    u64   lk[CAP6];                                // 64 KB
    float y1[NPOST], x1[NPOST], y2[NPOST], x2[NPOST], ar[NPOST];
};

#define RL(S, M) { unsigned lo_ = (unsigned)__builtin_amdgcn_readlane((int)(unsigned)(M), b); \
                   unsigned hi_ = (unsigned)__builtin_amdgcn_readlane((int)(unsigned)((M) >> 32), b); \
                   S |= (((u64)hi_ << 32) | (u64)lo_); }

#define SCAN_GROUP(G, SUPG) \
    if (!done) { \
        const int base = (G) * 64; \
        if (base < Ceff) { \
            u64 m0 = gmat[0*CA + base + tid], m1 = gmat[1*CA + base + tid]; \
            u64 m2 = gmat[2*CA + base + tid], m3 = gmat[3*CA + base + tid]; \
            u64 m4 = gmat[4*CA + base + tid], m5 = gmat[5*CA + base + tid]; \
            u64 m6 = gmat[6*CA + base + tid], m7 = gmat[7*CA + base + tid]; \
            u64 bound = (Ceff - base >= 64) ? ~0ULL : ((1ULL << (Ceff - base)) - 1ULL); \
            u64 live = ~SUPG & bound; \
            while (live) { \
                int b = (int)__builtin_ctzll(live); \
                if (tid == 0) skept[nk] = (unsigned)(base + b); \
                ++nk; \
                if (nk == NPOST) { done = true; break; } \
                RL(sup0, m0) RL(sup1, m1) RL(sup2, m2) RL(sup3, m3) \
                RL(sup4, m4) RL(sup5, m5) RL(sup6, m6) RL(sup7, m7) \
                live &= ~(1ULL << b); \
                live &= ~SUPG; \
            } \
        } else done = true; \
    }

// ---- 4: single block: serial ctz scan over bit-matrix + output (+gated fallback) ----
__global__ void __launch_bounds__(256) k_scan(
        const float4* __restrict__ loc, const float4* __restrict__ anchor,
        const int* __restrict__ ph, const int* __restrict__ pw, int n,
        const u64* __restrict__ cand6, const unsigned* __restrict__ cnts,
        const float4* __restrict__ roiA, const u64* __restrict__ vsup_g,
        const u64* __restrict__ gmat,
        unsigned* __restrict__ order6, float4* __restrict__ roi6,
        float* __restrict__ out) {
    __shared__ SmFb fb;
    __shared__ unsigned skept[NPOST];
    __shared__ int snk, sflag;
    int tid = threadIdx.x;
    unsigned cntA = cnts[0], cnt6 = cnts[1];
    bool mainValid = (cntA <= CAPA);
    int Ceff = (int)(cntA < (unsigned)CA ? cntA : (unsigned)CA);
    float ih = (float)ph[0], iw = (float)pw[0];

    if (tid < 64 && mainValid) {
        u64 sup0 = ~vsup_g[0], sup1 = ~vsup_g[1], sup2 = ~vsup_g[2], sup3 = ~vsup_g[3];
        u64 sup4 = ~vsup_g[4], sup5 = ~vsup_g[5], sup6 = ~vsup_g[6], sup7 = ~vsup_g[7];
        int nk = 0;
        bool done = false;
        SCAN_GROUP(0, sup0) SCAN_GROUP(1, sup1) SCAN_GROUP(2, sup2) SCAN_GROUP(3, sup3)
        SCAN_GROUP(4, sup4) SCAN_GROUP(5, sup5) SCAN_GROUP(6, sup6) SCAN_GROUP(7, sup7)
        if (tid == 0) {
            snk = nk;
            sflag = (nk < NPOST && cnt6 > (unsigned)Ceff) ? 1 : 0;
        }
    }
    if (tid == 0 && !mainValid) { snk = 0; sflag = 1; }
    __syncthreads();
    int nk = snk, flag = sflag;
    float4* out4 = (float4*)out;
    if (!flag) {
        for (int k = tid; k < NPOST; k += 256) {
            float4 o = make_float4(0.f, 0.f, 0.f, 0.f);
            if (k < nk) o = roiA[skept[k]];
            out4[k] = o;
        }
        return;
    }
    // ---------- exact fallback (gated; never taken on sane data) ----------
    unsigned M = cnt6 < (unsigned)CAP6 ? cnt6 : (unsigned)CAP6;
    for (unsigned i = tid; i < CAP6; i += 256) fb.lk[i] = (i < M) ? cand6[i] : ~0ULL;
    for (int r = tid; r < NPRE; r += 256) order6[r] = 0xFFFFFFFFu;
    __syncthreads();
    for (unsigned c = tid; c < M; c += 256) {
        u64 key = fb.lk[c];
        int rank = 0;
        for (unsigned j = 0; j < M; ++j) rank += (fb.lk[j] < key) ? 1 : 0;
        if (rank < NPRE) order6[rank] = (unsigned)key;
    }
    __syncthreads();
    for (int r = tid; r < NPRE; r += 256) {
        unsigned idx = order6[r];
        float4 b = make_float4(0.f, 0.f, 0.f, 0.f);
        if (idx < (unsigned)n) b = decode_box(anchor[idx], loc[idx], ih, iw);
        roi6[r] = b;
    }
    __syncthreads();
    if (tid < 64) {
        int lane = tid;
        int nk2 = 0;
        for (int i = 0; i < NPRE; i++) {
            float4 b = roi6[i];
            float hs = b.z - b.x, wd = b.w - b.y;
            if (!(hs >= MINSZ && wd >= MINSZ)) continue;
            float ab = hs * wd;
            bool sup = false;
            for (int base = 0; base < nk2 && !sup; base += 64) {
                int t = base + lane;
                bool s = false;
                if (t < nk2) {
                    float yy1 = fmaxf(b.x, fb.y1[t]);
                    float xx1 = fmaxf(b.y, fb.x1[t]);
                    float yy2 = fminf(b.z, fb.y2[t]);
                    float xx2 = fminf(b.w, fb.x2[t]);
                    float inter = fmaxf(yy2 - yy1, 0.0f) * fmaxf(xx2 - xx1, 0.0f);
                    float iou = inter / (fb.ar[t] + ab - inter);
                    s = iou > NMS_T;
                }
                sup = (__ballot(s) != 0ULL);
            }
            if (!sup) {
                if (lane == 0) {
                    fb.y1[nk2] = b.x; fb.x1[nk2] = b.y;
                    fb.y2[nk2] = b.z; fb.x2[nk2] = b.w; fb.ar[nk2] = ab;
                }
                nk2++;
                if (nk2 == NPOST) break;
            }
        }
        for (int k = lane; k < NPOST; k += 64) {
            float4 o = make_float4(0.f, 0.f, 0.f, 0.f);
            if (k < nk2) o = make_float4(fb.y1[k], fb.x1[k], fb.y2[k], fb.x2[k]);
            out4[k] = o;
        }
    }
}

extern "C" void kernel_launch(void* const* d_in, const int* in_sizes, int n_in,
                              void* d_out, int out_size, void* d_ws, size_t ws_size,
                              hipStream_t stream) {
    const float4* loc    = (const float4*)d_in[0];
    const float*  score  = (const float*)d_in[1];
    const float4* anchor = (const float4*)d_in[2];
    const int*    ph     = (const int*)d_in[3];
    const int*    pw     = (const int*)d_in[4];
    int n = in_sizes[1];

    char* ws = (char*)d_ws;
    u64*      cand6  = (u64*)(ws + OFF_CAND6);
    u64*      candA  = (u64*)(ws + OFF_CANDA);
    float4*   roiA   = (float4*)(ws + OFF_ROIA);
    u64*      vsup   = (u64*)(ws + OFF_VSUP);
    unsigned* order6 = (unsigned*)(ws + OFF_ORDER6);
    float4*   roi6   = (float4*)(ws + OFF_ROI6);
    u64*      gmat   = (u64*)(ws + OFF_GMAT);
    unsigned* h      = (unsigned*)(ws + OFF_H);
    unsigned* cnts   = (unsigned*)(ws + OFF_CNT);
    float* out = (float*)d_out;

    hipMemsetAsync(ws + OFF_H, 0, ZERO_BYTES, stream);
    k_hist    <<<dim3(128), dim3(256), 0, stream>>>(score, n, h);
    k_compact <<<dim3(128), dim3(256), 0, stream>>>(loc, score, anchor, ph, pw, n, h,
                                                    candA, cand6, cnts);
    k_rankmat <<<dim3(8),   dim3(256), 0, stream>>>(loc, anchor, ph, pw, candA, cnts,
                                                    gmat, roiA, vsup);
    k_scan    <<<dim3(1),   dim3(256), 0, stream>>>(loc, anchor, ph, pw, n, cand6, cnts,
                                                    roiA, vsup, gmat, order6, roi6, out);
}

// Round 7
// 128.120 us; speedup vs baseline: 3.3903x; 1.0492x over previous
//
#include <hip/hip_runtime.h>
#include <stdint.h>

typedef unsigned long long u64;

#define NMS_T 0.7f
#define MINSZ 16.0f
#define NPRE 6000
#define NPOST 300
#define CA   512
#define CAPA 2048
#define CAP6 8192
#define NBIN 2048
#define NSLOT 32

// ---- workspace layout (bytes) ----
#define OFF_CAND6  0                          // CAP6*8  = 65536
#define OFF_CANDA  (OFF_CAND6 + CAP6*8)       // CAPA*8  = 16384
#define OFF_ROIA   (OFF_CANDA + CAPA*8)       // CA*16   = 8192
#define OFF_VSUP   (OFF_ROIA + CA*16)         // 64  (VALID-bit mask, 8 u64)
#define OFF_ORDER6 (OFF_VSUP + 64)            // NPRE*4  (fallback)
#define OFF_ROI6   (OFF_ORDER6 + NPRE*4)      // NPRE*16 (fallback)
#define OFF_GMAT   (OFF_ROI6 + NPRE*16)       // CA*8*8 word-major gmat[w*CA+row]
#define OFF_SLOT   (OFF_GMAT + CA*64)         // NSLOT*NBIN*4 = 262144
#define OFF_CNT    (OFF_SLOT + NSLOT*NBIN*4)  // 32: [0]=cntA [1]=cnt6

__device__ __forceinline__ unsigned inv_key(float s) {
    unsigned u = __float_as_uint(s);
    unsigned k = (u & 0x80000000u) ? ~u : (u | 0x80000000u);
    return ~k;   // ascending inv == descending score
}

__device__ __forceinline__ float4 decode_box(const float4 a, const float4 l,
                                             float ih, float iw) {
    float h  = a.z - a.x;
    float w  = a.w - a.y;
    float cy = a.x + 0.5f * h;
    float cx = a.y + 0.5f * w;
    float ncy = l.x * h + cy;
    float ncx = l.y * w + cx;
    float nh  = expf(l.z) * h;
    float nw  = expf(l.w) * w;
    float y1 = fminf(fmaxf(ncy - 0.5f * nh, 0.0f), ih);
    float x1 = fminf(fmaxf(ncx - 0.5f * nw, 0.0f), iw);
    float y2 = fminf(fmaxf(ncy + 0.5f * nh, 0.0f), ih);
    float x2 = fminf(fmaxf(ncx + 0.5f * nw, 0.0f), iw);
    return make_float4(y1, x1, y2, x2);
}

__device__ __forceinline__ int sbin_of(float s) {
    int b = (int)(s * 2048.0f);
    b = b < 0 ? 0 : (b > 2047 ? 2047 : b);
    return 2047 - b;           // ascending = descending score
}

__device__ __forceinline__ u64 readlane64(u64 v, int lane) {
    unsigned lo = (unsigned)__builtin_amdgcn_readlane((int)(unsigned)v, lane);
    unsigned hi = (unsigned)__builtin_amdgcn_readlane((int)(unsigned)(v >> 32), lane);
    return ((u64)hi << 32) | (u64)lo;
}

// block-wide (256 threads) scan of 2048-bin histogram; bins containing ranks t0/t1
__device__ void scan2048(const unsigned* __restrict__ h, unsigned t0, unsigned t1,
                         unsigned* psum, unsigned* res, int base) {
    int t = threadIdx.x;
    unsigned vals[8];
    unsigned s = 0;
#pragma unroll
    for (int j = 0; j < 8; j++) { vals[j] = h[t * 8 + j]; s += vals[j]; }
    psum[t] = s;
    __syncthreads();
    for (int off = 1; off < 256; off <<= 1) {
        unsigned v = (t >= off) ? psum[t - off] : 0u;
        __syncthreads();
        psum[t] += v;
        __syncthreads();
    }
    unsigned run = (t == 0) ? 0u : psum[t - 1];
#pragma unroll
    for (int j = 0; j < 8; j++) {
        unsigned c = vals[j];
        if (run < t0 && run + c >= t0) { res[base + 0] = t * 8 + j; res[base + 1] = run; }
        if (t1 && run < t1 && run + c >= t1) { res[base + 2] = t * 8 + j; res[base + 3] = run; }
        run += c;
    }
    __syncthreads();
}

// ---- 1: score-only histogram into per-block slots (plain stores; no memset needed) ----
__global__ void __launch_bounds__(256) k_hist(const float* __restrict__ score, int n,
                                              unsigned* __restrict__ slots,
                                              unsigned* __restrict__ cnts) {
    __shared__ unsigned lh[NBIN];
    for (int b = threadIdx.x; b < NBIN; b += 256) lh[b] = 0;
    if (blockIdx.x == 0 && threadIdx.x < 8) cnts[threadIdx.x] = 0;
    __syncthreads();
    int gtid = blockIdx.x * 256 + threadIdx.x;
    int stride = gridDim.x * 256;
    int n4 = n >> 2;
    const float4* s4 = (const float4*)score;
    for (int i = gtid; i < n4; i += stride) {
        float4 s = s4[i];
        atomicAdd(&lh[sbin_of(s.x)], 1u);
        atomicAdd(&lh[sbin_of(s.y)], 1u);
        atomicAdd(&lh[sbin_of(s.z)], 1u);
        atomicAdd(&lh[sbin_of(s.w)], 1u);
    }
    for (int i = n4 * 4 + gtid; i < n; i += stride) atomicAdd(&lh[sbin_of(score[i])], 1u);
    __syncthreads();
    for (int b = threadIdx.x; b < NBIN; b += 256)
        slots[blockIdx.x * NBIN + b] = lh[b];
}

// ---- 2: sum slots -> thresholds -> two-phase compaction (decode only ~6.5K selected) ----
__global__ void __launch_bounds__(256) k_compact(
        const float4* __restrict__ loc, const float* __restrict__ score,
        const float4* __restrict__ anchor, const int* __restrict__ ph,
        const int* __restrict__ pw, int n, const unsigned* __restrict__ slots,
        u64* __restrict__ candA, u64* __restrict__ cand6, unsigned* __restrict__ cnts) {
    __shared__ unsigned hsum[NBIN];
    __shared__ unsigned psum[256];
    __shared__ unsigned res[8];
    __shared__ unsigned sbase[2];
    int tid = threadIdx.x;
    for (int b = tid; b < NBIN; b += 256) {
        unsigned s = 0;
#pragma unroll 4
        for (int sl = 0; sl < NSLOT; ++sl) s += slots[sl * NBIN + b];
        hsum[b] = s;
    }
    __syncthreads();
    scan2048(hsum, CA, NPRE, psum, res, 0);   // res0 = bA, res2 = b6
    unsigned bA = res[0], b6 = res[2];
    float ih = (float)ph[0], iw = (float)pw[0];
    int gtid = blockIdx.x * 256 + tid;
    int stride = gridDim.x * 256;
    unsigned cA = 0, c6 = 0;
    for (int i = gtid; i < n; i += stride) {
        unsigned hb = (unsigned)sbin_of(score[i]);
        c6 += (hb <= b6);
        cA += (hb <= bA);
    }
    psum[tid] = (cA << 16) | c6;
    __syncthreads();
    for (int off = 1; off < 256; off <<= 1) {
        unsigned v = (tid >= off) ? psum[tid - off] : 0u;
        __syncthreads();
        psum[tid] += v;
        __syncthreads();
    }
    if (tid == 0) {
        unsigned tot = psum[255];
        sbase[0] = atomicAdd(&cnts[1], tot & 0xFFFFu);
        sbase[1] = atomicAdd(&cnts[0], tot >> 16);
    }
    __syncthreads();
    unsigned excl = (tid == 0) ? 0u : psum[tid - 1];
    unsigned pos6 = sbase[0] + (excl & 0xFFFFu);
    unsigned posA = sbase[1] + (excl >> 16);
    for (int i = gtid; i < n; i += stride) {
        float s = score[i];
        unsigned hb = (unsigned)sbin_of(s);
        if (hb <= b6) {
            float4 r = decode_box(anchor[i], loc[i], ih, iw);
            bool valid = ((r.z - r.x) >= MINSZ) && ((r.w - r.y) >= MINSZ);
            float ms = valid ? s : -__builtin_inff();
            u64 key = ((u64)inv_key(ms) << 32) | (unsigned)i;
            if (pos6 < CAP6) cand6[pos6] = key;
            pos6++;
            if (hb <= bA) {
                if (posA < CAPA) candA[posA] = key;
                posA++;
            }
        }
    }
}

// register-blocked exact rank + decode of top-CA
template <int KB>
__device__ __forceinline__ void rank_block(const u64* lk2, unsigned MP,
                                           const float4* anchor, const float4* loc,
                                           float ih, float iw,
                                           float4* sroi, float* sarea, unsigned* svalid) {
    u64 kc[KB]; int rr[KB];
#pragma unroll
    for (int k = 0; k < KB; ++k) {
        unsigned c = threadIdx.x + k * 256u;
        kc[k] = (c < MP) ? lk2[c] : ~0ULL;
        rr[k] = 0;
    }
    for (unsigned j = 0; j < MP; ++j) {
        u64 kj = lk2[j];
#pragma unroll
        for (int k = 0; k < KB; ++k) rr[k] += (kj < kc[k]) ? 1 : 0;
    }
#pragma unroll
    for (int k = 0; k < KB; ++k) {
        unsigned c = threadIdx.x + k * 256u;
        if (c < MP && rr[k] < CA) {
            unsigned idx = (unsigned)kc[k];
            float4 b = decode_box(anchor[idx], loc[idx], ih, iw);
            sroi[rr[k]] = b;
            sarea[rr[k]] = (b.z - b.x) * (b.w - b.y);
            if (((b.z - b.x) >= MINSZ) && ((b.w - b.y) >= MINSZ))
                atomicOr(&svalid[rr[k] >> 5], 1u << (rr[k] & 31));
        }
    }
}

// ---- 3: 8 parallel blocks: prune -> rank -> decode -> matrix slice ----
__global__ void __launch_bounds__(256) k_rankmat(
        const float4* __restrict__ loc, const float4* __restrict__ anchor,
        const int* __restrict__ ph, const int* __restrict__ pw,
        const u64* __restrict__ candA, const unsigned* __restrict__ cnts,
        u64* __restrict__ gmat, float4* __restrict__ roiA, u64* __restrict__ vsup_g) {
    __shared__ u64 lk[CAPA];
    __shared__ u64 lk2[CAPA];
    __shared__ unsigned shist[NBIN];
    __shared__ float4 sroi[CA];
    __shared__ float sarea[CA];
    __shared__ unsigned svalid[CA / 32];
    __shared__ unsigned psum[256];
    __shared__ unsigned res2[8];
    __shared__ unsigned sInvLo, sMP;
    int tid = threadIdx.x;
    unsigned cntA = cnts[0];
    if (cntA > CAPA) return;                      // flag path handled in k_scan
    unsigned MA = cntA;
    float ih = (float)ph[0], iw = (float)pw[0];

    if (tid == 0) { sInvLo = 0xFFFFFFFFu; sMP = 0; res2[0] = NBIN - 1; }
    for (int b = tid; b < NBIN; b += 256) shist[b] = 0;
    for (int r = tid; r < CA; r += 256) { sroi[r] = make_float4(0.f,0.f,0.f,0.f); sarea[r] = 0.f; }
    if (tid < CA / 32) svalid[tid] = 0;
    __syncthreads();
    for (unsigned i = tid; i < MA; i += 256) {
        u64 k = candA[i];
        lk[i] = k;
        atomicMin(&sInvLo, (unsigned)(k >> 32));
    }
    __syncthreads();
    unsigned invLo = sInvLo;
    for (unsigned i = tid; i < MA; i += 256) {
        unsigned d = ((unsigned)(lk[i] >> 32) - invLo) >> 3;
        atomicAdd(&shist[d > 2047u ? 2047u : d], 1u);
    }
    __syncthreads();
    scan2048(shist, CA, 0, psum, res2, 0);        // res2[0] = sub-bin threshold
    unsigned sbT = res2[0];
    for (unsigned i = tid; i < MA; i += 256) {
        unsigned d = ((unsigned)(lk[i] >> 32) - invLo) >> 3;
        if ((d > 2047u ? 2047u : d) <= sbT) lk2[atomicAdd(&sMP, 1u)] = lk[i];
    }
    __syncthreads();
    unsigned MP = sMP;                             // >= min(512, MA), typically ~520
    if (MP <= 1024) rank_block<4>(lk2, MP, anchor, loc, ih, iw, sroi, sarea, svalid);
    else            rank_block<8>(lk2, MP, anchor, loc, ih, iw, sroi, sarea, svalid);
    __syncthreads();
    int w = blockIdx.x;
    int j0 = w * 64;
#pragma unroll
    for (int rrr = 0; rrr < 2; ++rrr) {
        int row = tid + rrr * 256;
        u64 bits = 0;
        if (j0 + 63 > row) {
            float4 b = sroi[row];
            float ab = sarea[row];
#pragma unroll 4
            for (int jj = 0; jj < 64; ++jj) {
                int j = j0 + jj;
                if (j > row) {
                    float4 c = sroi[j];
                    float yy1 = fmaxf(b.x, c.x);
                    float xx1 = fmaxf(b.y, c.y);
                    float yy2 = fminf(b.z, c.z);
                    float xx2 = fminf(b.w, c.w);
                    float inter = fmaxf(yy2 - yy1, 0.0f) * fmaxf(xx2 - xx1, 0.0f);
                    float iou = inter / (ab + sarea[j] - inter);  // ref op order
                    if (iou > NMS_T) bits |= (1ULL << jj);
                }
            }
        }
        gmat[w * CA + row] = bits;
    }
    if (blockIdx.x == 0) {
        for (int r = tid; r < CA; r += 256) roiA[r] = sroi[r];
        if (tid < 8) vsup_g[tid] = ((u64)svalid[2 * tid + 1] << 32) | (u64)svalid[2 * tid];
    }
}

struct SmFb {
    u64   lk[CAP6];                                // 64 KB
    float y1[NPOST], x1[NPOST], y2[NPOST], x2[NPOST], ar[NPOST];
};

// ---- 4: single block: group-serial scan, O(1) per kept + deferred butterfly fold ----
__global__ void __launch_bounds__(256) k_scan(
        const float4* __restrict__ loc, const float4* __restrict__ anchor,
        const int* __restrict__ ph, const int* __restrict__ pw, int n,
        const u64* __restrict__ cand6, const unsigned* __restrict__ cnts,
        const float4* __restrict__ roiA, const u64* __restrict__ vsup_g,
        const u64* __restrict__ gmat,
        unsigned* __restrict__ order6, float4* __restrict__ roi6,
        float* __restrict__ out) {
    __shared__ SmFb fb;
    __shared__ u64 skm[8];
    __shared__ int snk, sflag;
    int tid = threadIdx.x;
    unsigned cntA = cnts[0], cnt6 = cnts[1];
    bool mainValid = (cntA <= CAPA);
    int Ceff = (int)(cntA < (unsigned)CA ? cntA : (unsigned)CA);
    float ih = (float)ph[0], iw = (float)pw[0];

    if (tid < 64 && mainValid) {
        u64 supfut[8], curM[8], nxtM[8], kmask[8];
#pragma unroll
        for (int w = 0; w < 8; ++w) { supfut[w] = ~vsup_g[w]; kmask[w] = 0ull; }
#pragma unroll
        for (int w = 0; w < 8; ++w) curM[w] = gmat[w * CA + tid];
        int nk = 0;
        bool done = false;
#pragma unroll
        for (int g = 0; g < 8; ++g) {
            if (g < 7) {
#pragma unroll
                for (int w = 0; w < 8; ++w) nxtM[w] = gmat[w * CA + 64 * (g + 1) + tid];
            }
            int base = 64 * g;
            if (!done && base < Ceff) {
                u64 bound = (Ceff - base >= 64) ? ~0ull : ((1ull << (Ceff - base)) - 1ull);
                u64 live = ~supfut[g] & bound;
                u64 km = 0;
                while (live) {
                    int b = (int)__builtin_ctzll(live);
                    km |= (1ull << b);
                    ++nk;
                    if (nk == NPOST) { done = true; break; }
                    u64 row = readlane64(curM[g], b);   // word g of kept row: 2 readlanes
                    live &= ~(row | (1ull << b));
                }
                kmask[g] = km;
                if (!done && g < 7) {                   // deferred cross-group fold
                    bool mk = ((km >> tid) & 1ull) != 0ull;
                    u64 c[8];
#pragma unroll
                    for (int w = g + 1; w < 8; ++w) c[w] = mk ? curM[w] : 0ull;
#pragma unroll
                    for (int off = 1; off < 64; off <<= 1) {
#pragma unroll
                        for (int w = g + 1; w < 8; ++w) c[w] |= __shfl_xor(c[w], off, 64);
                    }
#pragma unroll
                    for (int w = g + 1; w < 8; ++w) supfut[w] |= c[w];
                }
            }
#pragma unroll
            for (int w = 0; w < 8; ++w) curM[w] = nxtM[w];
        }
        if (tid == 0) {
            snk = nk;
            sflag = (nk < NPOST && cnt6 > (unsigned)Ceff) ? 1 : 0;
            skm[0] = kmask[0]; skm[1] = kmask[1]; skm[2] = kmask[2]; skm[3] = kmask[3];
            skm[4] = kmask[4]; skm[5] = kmask[5]; skm[6] = kmask[6]; skm[7] = kmask[7];
        }
    }
    if (tid == 0 && !mainValid) {
        snk = 0; sflag = 1;
        skm[0]=0; skm[1]=0; skm[2]=0; skm[3]=0; skm[4]=0; skm[5]=0; skm[6]=0; skm[7]=0;
    }
    __syncthreads();
    int nk = snk, flag = sflag;
    float4* out4 = (float4*)out;
    if (!flag) {
        int basepc[8];
        {
            int run = 0;
#pragma unroll
            for (int g = 0; g < 8; ++g) { basepc[g] = run; run += __popcll(skm[g]); }
        }
        int wv = tid >> 6, j = tid & 63;
#pragma unroll
        for (int gg = 0; gg < 2; ++gg) {
            int g = wv * 2 + gg;
            u64 km = skm[g];
            if ((km >> j) & 1ull) {
                int rank = basepc[g] + __popcll(km & ((1ull << j) - 1ull));
                if (rank < NPOST) out4[rank] = roiA[64 * g + j];
            }
        }
        for (int k = nk + tid; k < NPOST; k += 256) out4[k] = make_float4(0.f,0.f,0.f,0.f);
        return;
    }
    // ---------- exact fallback (gated; never taken on sane data) ----------
    unsigned M = cnt6 < (unsigned)CAP6 ? cnt6 : (unsigned)CAP6;
    for (unsigned i = tid; i < CAP6; i += 256) fb.lk[i] = (i < M) ? cand6[i] : ~0ULL;
    for (int r = tid; r < NPRE; r += 256) order6[r] = 0xFFFFFFFFu;
    __syncthreads();
    for (unsigned c = tid; c < M; c += 256) {
        u64 key = fb.lk[c];
        int rank = 0;
        for (unsigned j = 0; j < M; ++j) rank += (fb.lk[j] < key) ? 1 : 0;
        if (rank < NPRE) order6[rank] = (unsigned)key;
    }
    __syncthreads();
    for (int r = tid; r < NPRE; r += 256) {
        unsigned idx = order6[r];
        float4 b = make_float4(0.f, 0.f, 0.f, 0.f);
        if (idx < (unsigned)n) b = decode_box(anchor[idx], loc[idx], ih, iw);
        roi6[r] = b;
    }
    __syncthreads();
    if (tid < 64) {
        int lane = tid;
        int nk2 = 0;
        for (int i = 0; i < NPRE; i++) {
            float4 b = roi6[i];
            float hs = b.z - b.x, wd = b.w - b.y;
            if (!(hs >= MINSZ && wd >= MINSZ)) continue;
            float ab = hs * wd;
            bool sup = false;
            for (int base = 0; base < nk2 && !sup; base += 64) {
                int t = base + lane;
                bool s = false;
                if (t < nk2) {
                    float yy1 = fmaxf(b.x, fb.y1[t]);
                    float xx1 = fmaxf(b.y, fb.x1[t]);
                    float yy2 = fminf(b.z, fb.y2[t]);
                    float xx2 = fminf(b.w, fb.x2[t]);
                    float inter = fmaxf(yy2 - yy1, 0.0f) * fmaxf(xx2 - xx1, 0.0f);
                    float iou = inter / (fb.ar[t] + ab - inter);
                    s = iou > NMS_T;
                }
                sup = (__ballot(s) != 0ULL);
            }
            if (!sup) {
                if (lane == 0) {
                    fb.y1[nk2] = b.x; fb.x1[nk2] = b.y;
                    fb.y2[nk2] = b.z; fb.x2[nk2] = b.w; fb.ar[nk2] = ab;
                }
                nk2++;
                if (nk2 == NPOST) break;
            }
        }
        for (int k = lane; k < NPOST; k += 64) {
            float4 o = make_float4(0.f, 0.f, 0.f, 0.f);
            if (k < nk2) o = make_float4(fb.y1[k], fb.x1[k], fb.y2[k], fb.x2[k]);
            out4[k] = o;
        }
    }
}

extern "C" void kernel_launch(void* const* d_in, const int* in_sizes, int n_in,
                              void* d_out, int out_size, void* d_ws, size_t ws_size,
                              hipStream_t stream) {
    const float4* loc    = (const float4*)d_in[0];
    const float*  score  = (const float*)d_in[1];
    const float4* anchor = (const float4*)d_in[2];
    const int*    ph     = (const int*)d_in[3];
    const int*    pw     = (const int*)d_in[4];
    int n = in_sizes[1];

    char* ws = (char*)d_ws;
    u64*      cand6  = (u64*)(ws + OFF_CAND6);
    u64*      candA  = (u64*)(ws + OFF_CANDA);
    float4*   roiA   = (float4*)(ws + OFF_ROIA);
    u64*      vsup   = (u64*)(ws + OFF_VSUP);
    unsigned* order6 = (unsigned*)(ws + OFF_ORDER6);
    float4*   roi6   = (float4*)(ws + OFF_ROI6);
    u64*      gmat   = (u64*)(ws + OFF_GMAT);
    unsigned* slots  = (unsigned*)(ws + OFF_SLOT);
    unsigned* cnts   = (unsigned*)(ws + OFF_CNT);
    float* out = (float*)d_out;

    k_hist    <<<dim3(NSLOT), dim3(256), 0, stream>>>(score, n, slots, cnts);
    k_compact <<<dim3(128),   dim3(256), 0, stream>>>(loc, score, anchor, ph, pw, n, slots,
                                                      candA, cand6, cnts);
    k_rankmat <<<dim3(8),     dim3(256), 0, stream>>>(loc, anchor, ph, pw, candA, cnts,
                                                      gmat, roiA, vsup);
    k_scan    <<<dim3(1),     dim3(256), 0, stream>>>(loc, anchor, ph, pw, n, cand6, cnts,
                                                      roiA, vsup, gmat, order6, roi6, out);
}

// Round 8
// 120.494 us; speedup vs baseline: 3.6048x; 1.0633x over previous
//
#include <hip/hip_runtime.h>
#include <stdint.h>

typedef unsigned long long u64;

#define NMS_T 0.7f
#define MINSZ 16.0f
#define NPRE 6000
#define NPOST 300
#define CA   512
#define CAPA 2048
#define CAP6 8192
#define NBIN 2048
#define NSLOT 32

// ---- workspace layout (bytes) ----
#define OFF_CAND6  0                          // CAP6*8  = 65536
#define OFF_CANDA  (OFF_CAND6 + CAP6*8)       // CAPA*8  = 16384
#define OFF_ROIA   (OFF_CANDA + CAPA*8)       // CA*16   = 8192
#define OFF_VSUP   (OFF_ROIA + CA*16)         // 64  (VALID-bit mask, 8 u64)
#define OFF_ORDER6 (OFF_VSUP + 64)            // NPRE*4  (fallback)
#define OFF_ROI6   (OFF_ORDER6 + NPRE*4)      // NPRE*16 (fallback)
#define OFF_GMAT   (OFF_ROI6 + NPRE*16)       // CA*8*8 word-major gmat[w*CA+row]
#define OFF_SLOT   (OFF_GMAT + CA*64)         // NSLOT*NBIN*4 = 262144
#define OFF_CNT    (OFF_SLOT + NSLOT*NBIN*4)  // 32: [0]=cntA [1]=cnt6

__device__ __forceinline__ unsigned inv_key(float s) {
    unsigned u = __float_as_uint(s);
    unsigned k = (u & 0x80000000u) ? ~u : (u | 0x80000000u);
    return ~k;   // ascending inv == descending score
}

__device__ __forceinline__ float4 decode_box(const float4 a, const float4 l,
                                             float ih, float iw) {
    float h  = a.z - a.x;
    float w  = a.w - a.y;
    float cy = a.x + 0.5f * h;
    float cx = a.y + 0.5f * w;
    float ncy = l.x * h + cy;
    float ncx = l.y * w + cx;
    float nh  = expf(l.z) * h;
    float nw  = expf(l.w) * w;
    float y1 = fminf(fmaxf(ncy - 0.5f * nh, 0.0f), ih);
    float x1 = fminf(fmaxf(ncx - 0.5f * nw, 0.0f), iw);
    float y2 = fminf(fmaxf(ncy + 0.5f * nh, 0.0f), ih);
    float x2 = fminf(fmaxf(ncx + 0.5f * nw, 0.0f), iw);
    return make_float4(y1, x1, y2, x2);
}

__device__ __forceinline__ int sbin_of(float s) {
    int b = (int)(s * 2048.0f);
    b = b < 0 ? 0 : (b > 2047 ? 2047 : b);
    return 2047 - b;           // ascending = descending score
}

__device__ __forceinline__ u64 readlane64(u64 v, int lane) {
    unsigned lo = (unsigned)__builtin_amdgcn_readlane((int)(unsigned)v, lane);
    unsigned hi = (unsigned)__builtin_amdgcn_readlane((int)(unsigned)(v >> 32), lane);
    return ((u64)hi << 32) | (u64)lo;
}

// block-wide (256 threads) scan of 2048-bin histogram; bins containing ranks t0/t1
__device__ void scan2048(const unsigned* __restrict__ h, unsigned t0, unsigned t1,
                         unsigned* psum, unsigned* res, int base) {
    int t = threadIdx.x;
    unsigned vals[8];
    unsigned s = 0;
#pragma unroll
    for (int j = 0; j < 8; j++) { vals[j] = h[t * 8 + j]; s += vals[j]; }
    psum[t] = s;
    __syncthreads();
    for (int off = 1; off < 256; off <<= 1) {
        unsigned v = (t >= off) ? psum[t - off] : 0u;
        __syncthreads();
        psum[t] += v;
        __syncthreads();
    }
    unsigned run = (t == 0) ? 0u : psum[t - 1];
#pragma unroll
    for (int j = 0; j < 8; j++) {
        unsigned c = vals[j];
        if (run < t0 && run + c >= t0) { res[base + 0] = t * 8 + j; res[base + 1] = run; }
        if (t1 && run < t1 && run + c >= t1) { res[base + 2] = t * 8 + j; res[base + 3] = run; }
        run += c;
    }
    __syncthreads();
}

// ---- 1: score-only histogram into per-block slots (plain stores; no memset needed) ----
__global__ void __launch_bounds__(256) k_hist(const float* __restrict__ score, int n,
                                              unsigned* __restrict__ slots,
                                              unsigned* __restrict__ cnts) {
    __shared__ unsigned lh[NBIN];
    for (int b = threadIdx.x; b < NBIN; b += 256) lh[b] = 0;
    if (blockIdx.x == 0 && threadIdx.x < 8) cnts[threadIdx.x] = 0;
    __syncthreads();
    int gtid = blockIdx.x * 256 + threadIdx.x;
    int stride = gridDim.x * 256;
    int n4 = n >> 2;
    const float4* s4 = (const float4*)score;
    for (int i = gtid; i < n4; i += stride) {
        float4 s = s4[i];
        atomicAdd(&lh[sbin_of(s.x)], 1u);
        atomicAdd(&lh[sbin_of(s.y)], 1u);
        atomicAdd(&lh[sbin_of(s.z)], 1u);
        atomicAdd(&lh[sbin_of(s.w)], 1u);
    }
    for (int i = n4 * 4 + gtid; i < n; i += stride) atomicAdd(&lh[sbin_of(score[i])], 1u);
    __syncthreads();
    for (int b = threadIdx.x; b < NBIN; b += 256)
        slots[blockIdx.x * NBIN + b] = lh[b];
}

// ---- 2: sum slots -> thresholds -> two-phase compaction (decode only ~6.5K selected) ----
__global__ void __launch_bounds__(256) k_compact(
        const float4* __restrict__ loc, const float* __restrict__ score,
        const float4* __restrict__ anchor, const int* __restrict__ ph,
        const int* __restrict__ pw, int n, const unsigned* __restrict__ slots,
        u64* __restrict__ candA, u64* __restrict__ cand6, unsigned* __restrict__ cnts) {
    __shared__ unsigned hsum[NBIN];
    __shared__ unsigned psum[256];
    __shared__ unsigned res[8];
    __shared__ unsigned sbase[2];
    int tid = threadIdx.x;
    for (int b = tid; b < NBIN; b += 256) {
        unsigned s = 0;
#pragma unroll 4
        for (int sl = 0; sl < NSLOT; ++sl) s += slots[sl * NBIN + b];
        hsum[b] = s;
    }
    __syncthreads();
    scan2048(hsum, CA, NPRE, psum, res, 0);   // res0 = bA, res2 = b6
    unsigned bA = res[0], b6 = res[2];
    float ih = (float)ph[0], iw = (float)pw[0];
    int gtid = blockIdx.x * 256 + tid;
    int stride = gridDim.x * 256;
    unsigned cA = 0, c6 = 0;
    for (int i = gtid; i < n; i += stride) {
        unsigned hb = (unsigned)sbin_of(score[i]);
        c6 += (hb <= b6);
        cA += (hb <= bA);
    }
    psum[tid] = (cA << 16) | c6;
    __syncthreads();
    for (int off = 1; off < 256; off <<= 1) {
        unsigned v = (tid >= off) ? psum[tid - off] : 0u;
        __syncthreads();
        psum[tid] += v;
        __syncthreads();
    }
    if (tid == 0) {
        unsigned tot = psum[255];
        sbase[0] = atomicAdd(&cnts[1], tot & 0xFFFFu);
        sbase[1] = atomicAdd(&cnts[0], tot >> 16);
    }
    __syncthreads();
    unsigned excl = (tid == 0) ? 0u : psum[tid - 1];
    unsigned pos6 = sbase[0] + (excl & 0xFFFFu);
    unsigned posA = sbase[1] + (excl >> 16);
    for (int i = gtid; i < n; i += stride) {
        float s = score[i];
        unsigned hb = (unsigned)sbin_of(s);
        if (hb <= b6) {
            float4 r = decode_box(anchor[i], loc[i], ih, iw);
            bool valid = ((r.z - r.x) >= MINSZ) && ((r.w - r.y) >= MINSZ);
            float ms = valid ? s : -__builtin_inff();
            u64 key = ((u64)inv_key(ms) << 32) | (unsigned)i;
            if (pos6 < CAP6) cand6[pos6] = key;
            pos6++;
            if (hb <= bA) {
                if (posA < CAPA) candA[posA] = key;
                posA++;
            }
        }
    }
}

// register-blocked exact rank + decode of top-CA; j-loop batched 16-wide to break
// the per-iteration LDS latency chain (broadcast reads, independent)
template <int KB>
__device__ __forceinline__ void rank_block(const u64* lk2, unsigned MP,
                                           const float4* anchor, const float4* loc,
                                           float ih, float iw,
                                           float4* sroi, float* sarea, unsigned* svalid) {
    u64 kc[KB]; int rr[KB];
#pragma unroll
    for (int k = 0; k < KB; ++k) {
        unsigned c = threadIdx.x + k * 256u;
        kc[k] = (c < MP) ? lk2[c] : ~0ULL;
        rr[k] = 0;
    }
    unsigned j = 0;
    for (; j + 16 <= MP; j += 16) {
        u64 kj[16];
#pragma unroll
        for (int t = 0; t < 16; ++t) kj[t] = lk2[j + t];
#pragma unroll
        for (int t = 0; t < 16; ++t) {
#pragma unroll
            for (int k = 0; k < KB; ++k) rr[k] += (kj[t] < kc[k]) ? 1 : 0;
        }
    }
    for (; j < MP; ++j) {
        u64 kj = lk2[j];
#pragma unroll
        for (int k = 0; k < KB; ++k) rr[k] += (kj < kc[k]) ? 1 : 0;
    }
#pragma unroll
    for (int k = 0; k < KB; ++k) {
        unsigned c = threadIdx.x + k * 256u;
        if (c < MP && rr[k] < CA) {
            unsigned idx = (unsigned)kc[k];
            float4 b = decode_box(anchor[idx], loc[idx], ih, iw);
            sroi[rr[k]] = b;
            sarea[rr[k]] = (b.z - b.x) * (b.w - b.y);
            if (((b.z - b.x) >= MINSZ) && ((b.w - b.y) >= MINSZ))
                atomicOr(&svalid[rr[k] >> 5], 1u << (rr[k] & 31));
        }
    }
}

// ---- 3: 8 parallel blocks: prune -> rank -> decode -> matrix slice ----
__global__ void __launch_bounds__(256) k_rankmat(
        const float4* __restrict__ loc, const float4* __restrict__ anchor,
        const int* __restrict__ ph, const int* __restrict__ pw,
        const u64* __restrict__ candA, const unsigned* __restrict__ cnts,
        u64* __restrict__ gmat, float4* __restrict__ roiA, u64* __restrict__ vsup_g) {
    __shared__ u64 lk[CAPA];
    __shared__ u64 lk2[CAPA];
    __shared__ unsigned shist[NBIN];
    __shared__ float4 sroi[CA];
    __shared__ float sarea[CA];
    __shared__ unsigned svalid[CA / 32];
    __shared__ unsigned psum[256];
    __shared__ unsigned res2[8];
    __shared__ unsigned sInvLo, sMP;
    int tid = threadIdx.x;
    unsigned cntA = cnts[0];
    if (cntA > CAPA) return;                      // flag path handled in k_scan
    unsigned MA = cntA;
    float ih = (float)ph[0], iw = (float)pw[0];

    if (tid == 0) { sInvLo = 0xFFFFFFFFu; sMP = 0; res2[0] = NBIN - 1; }
    for (int b = tid; b < NBIN; b += 256) shist[b] = 0;
    for (int r = tid; r < CA; r += 256) { sroi[r] = make_float4(0.f,0.f,0.f,0.f); sarea[r] = 0.f; }
    if (tid < CA / 32) svalid[tid] = 0;
    __syncthreads();
    // load keys + wave-reduced min (4 LDS atomics total, not MA)
    unsigned mymin = 0xFFFFFFFFu;
    for (unsigned i = tid; i < MA; i += 256) {
        u64 k = candA[i];
        lk[i] = k;
        unsigned hi = (unsigned)(k >> 32);
        mymin = mymin < hi ? mymin : hi;
    }
#pragma unroll
    for (int off = 32; off; off >>= 1) {
        unsigned o = (unsigned)__shfl_down((int)mymin, off, 64);
        mymin = mymin < o ? mymin : o;
    }
    if ((tid & 63) == 0) atomicMin(&sInvLo, mymin);
    __syncthreads();
    unsigned invLo = sInvLo;
    for (unsigned i = tid; i < MA; i += 256) {
        unsigned d = ((unsigned)(lk[i] >> 32) - invLo) >> 3;
        atomicAdd(&shist[d > 2047u ? 2047u : d], 1u);
    }
    __syncthreads();
    scan2048(shist, CA, 0, psum, res2, 0);        // res2[0] = sub-bin threshold
    unsigned sbT = res2[0];
    // ballot-compact winners into lk2 (1 atomic per wave per pass; order irrelevant)
    unsigned MAr = (MA + 255u) & ~255u;
    for (unsigned i = tid; i < MAr; i += 256) {
        bool win = false;
        u64 key = 0;
        if (i < MA) {
            key = lk[i];
            unsigned d = ((unsigned)(key >> 32) - invLo) >> 3;
            win = ((d > 2047u ? 2047u : d) <= sbT);
        }
        u64 mask = __ballot(win);
        unsigned base = 0;
        if ((tid & 63) == 0 && mask) base = atomicAdd(&sMP, (unsigned)__popcll(mask));
        base = (unsigned)__builtin_amdgcn_readfirstlane((int)base);
        if (win) {
            unsigned pos = base + (unsigned)__popcll(mask & ((1ull << (tid & 63)) - 1ull));
            lk2[pos] = key;
        }
    }
    __syncthreads();
    unsigned MP = sMP;                             // >= min(512, MA), typically ~520
    if (MP <= 1024) rank_block<4>(lk2, MP, anchor, loc, ih, iw, sroi, sarea, svalid);
    else            rank_block<8>(lk2, MP, anchor, loc, ih, iw, sroi, sarea, svalid);
    __syncthreads();
    int w = blockIdx.x;
    int j0 = w * 64;
#pragma unroll
    for (int rrr = 0; rrr < 2; ++rrr) {
        int row = tid + rrr * 256;
        u64 bits = 0;
        if (j0 + 63 > row) {
            float4 b = sroi[row];
            float ab = sarea[row];
#pragma unroll 4
            for (int jj = 0; jj < 64; ++jj) {
                int j = j0 + jj;
                if (j > row) {
                    float4 c = sroi[j];
                    float yy1 = fmaxf(b.x, c.x);
                    float xx1 = fmaxf(b.y, c.y);
                    float yy2 = fminf(b.z, c.z);
                    float xx2 = fminf(b.w, c.w);
                    float inter = fmaxf(yy2 - yy1, 0.0f) * fmaxf(xx2 - xx1, 0.0f);
                    float iou = inter / (ab + sarea[j] - inter);  // ref op order
                    if (iou > NMS_T) bits |= (1ULL << jj);
                }
            }
        }
        gmat[w * CA + row] = bits;
    }
    if (blockIdx.x == 0) {
        for (int r = tid; r < CA; r += 256) roiA[r] = sroi[r];
        if (tid < 8) vsup_g[tid] = ((u64)svalid[2 * tid + 1] << 32) | (u64)svalid[2 * tid];
    }
}

struct SmFb {
    u64   lk[CAP6];                                // 64 KB
    float y1[NPOST], x1[NPOST], y2[NPOST], x2[NPOST], ar[NPOST];
};

// ---- 4: single block: group-serial scan, O(1) per kept + deferred butterfly fold ----
__global__ void __launch_bounds__(256) k_scan(
        const float4* __restrict__ loc, const float4* __restrict__ anchor,
        const int* __restrict__ ph, const int* __restrict__ pw, int n,
        const u64* __restrict__ cand6, const unsigned* __restrict__ cnts,
        const float4* __restrict__ roiA, const u64* __restrict__ vsup_g,
        const u64* __restrict__ gmat,
        unsigned* __restrict__ order6, float4* __restrict__ roi6,
        float* __restrict__ out) {
    __shared__ SmFb fb;
    __shared__ u64 skm[8];
    __shared__ int snk, sflag;
    int tid = threadIdx.x;
    unsigned cntA = cnts[0], cnt6 = cnts[1];
    bool mainValid = (cntA <= CAPA);
    int Ceff = (int)(cntA < (unsigned)CA ? cntA : (unsigned)CA);
    float ih = (float)ph[0], iw = (float)pw[0];

    if (tid < 64 && mainValid) {
        u64 supfut[8], curM[8], nxtM[8], kmask[8];
#pragma unroll
        for (int w = 0; w < 8; ++w) { supfut[w] = ~vsup_g[w]; kmask[w] = 0ull; }
#pragma unroll
        for (int w = 0; w < 8; ++w) curM[w] = gmat[w * CA + tid];
        int nk = 0;
        bool done = false;
#pragma unroll
        for (int g = 0; g < 8; ++g) {
            if (g < 7) {
#pragma unroll
                for (int w = 0; w < 8; ++w) nxtM[w] = gmat[w * CA + 64 * (g + 1) + tid];
            }
            int base = 64 * g;
            if (!done && base < Ceff) {
                u64 bound = (Ceff - base >= 64) ? ~0ull : ((1ull << (Ceff - base)) - 1ull);
                u64 live = ~supfut[g] & bound;
                u64 km = 0;
                while (live) {
                    int b = (int)__builtin_ctzll(live);
                    km |= (1ull << b);
                    ++nk;
                    if (nk == NPOST) { done = true; break; }
                    u64 row = readlane64(curM[g], b);   // word g of kept row: 2 readlanes
                    live &= ~(row | (1ull << b));
                }
                kmask[g] = km;
                if (!done && g < 7) {                   // deferred cross-group fold
                    bool mk = ((km >> tid) & 1ull) != 0ull;
                    u64 c[8];
#pragma unroll
                    for (int w = g + 1; w < 8; ++w) c[w] = mk ? curM[w] : 0ull;
#pragma unroll
                    for (int off = 1; off < 64; off <<= 1) {
#pragma unroll
                        for (int w = g + 1; w < 8; ++w) c[w] |= __shfl_xor(c[w], off, 64);
                    }
#pragma unroll
                    for (int w = g + 1; w < 8; ++w) supfut[w] |= c[w];
                }
            }
#pragma unroll
            for (int w = 0; w < 8; ++w) curM[w] = nxtM[w];
        }
        if (tid == 0) {
            snk = nk;
            sflag = (nk < NPOST && cnt6 > (unsigned)Ceff) ? 1 : 0;
            skm[0] = kmask[0]; skm[1] = kmask[1]; skm[2] = kmask[2]; skm[3] = kmask[3];
            skm[4] = kmask[4]; skm[5] = kmask[5]; skm[6] = kmask[6]; skm[7] = kmask[7];
        }
    }
    if (tid == 0 && !mainValid) {
        snk = 0; sflag = 1;
        skm[0]=0; skm[1]=0; skm[2]=0; skm[3]=0; skm[4]=0; skm[5]=0; skm[6]=0; skm[7]=0;
    }
    __syncthreads();
    int nk = snk, flag = sflag;
    float4* out4 = (float4*)out;
    if (!flag) {
        int basepc[8];
        {
            int run = 0;
#pragma unroll
            for (int g = 0; g < 8; ++g) { basepc[g] = run; run += __popcll(skm[g]); }
        }
        int wv = tid >> 6, j = tid & 63;
#pragma unroll
        for (int gg = 0; gg < 2; ++gg) {
            int g = wv * 2 + gg;
            u64 km = skm[g];
            if ((km >> j) & 1ull) {
                int rank = basepc[g] + __popcll(km & ((1ull << j) - 1ull));
                if (rank < NPOST) out4[rank] = roiA[64 * g + j];
            }
        }
        for (int k = nk + tid; k < NPOST; k += 256) out4[k] = make_float4(0.f,0.f,0.f,0.f);
        return;
    }
    // ---------- exact fallback (gated; never taken on sane data) ----------
    unsigned M = cnt6 < (unsigned)CAP6 ? cnt6 : (unsigned)CAP6;
    for (unsigned i = tid; i < CAP6; i += 256) fb.lk[i] = (i < M) ? cand6[i] : ~0ULL;
    for (int r = tid; r < NPRE; r += 256) order6[r] = 0xFFFFFFFFu;
    __syncthreads();
    for (unsigned c = tid; c < M; c += 256) {
        u64 key = fb.lk[c];
        int rank = 0;
        for (unsigned j = 0; j < M; ++j) rank += (fb.lk[j] < key) ? 1 : 0;
        if (rank < NPRE) order6[rank] = (unsigned)key;
    }
    __syncthreads();
    for (int r = tid; r < NPRE; r += 256) {
        unsigned idx = order6[r];
        float4 b = make_float4(0.f, 0.f, 0.f, 0.f);
        if (idx < (unsigned)n) b = decode_box(anchor[idx], loc[idx], ih, iw);
        roi6[r] = b;
    }
    __syncthreads();
    if (tid < 64) {
        int lane = tid;
        int nk2 = 0;
        for (int i = 0; i < NPRE; i++) {
            float4 b = roi6[i];
            float hs = b.z - b.x, wd = b.w - b.y;
            if (!(hs >= MINSZ && wd >= MINSZ)) continue;
            float ab = hs * wd;
            bool sup = false;
            for (int base = 0; base < nk2 && !sup; base += 64) {
                int t = base + lane;
                bool s = false;
                if (t < nk2) {
                    float yy1 = fmaxf(b.x, fb.y1[t]);
                    float xx1 = fmaxf(b.y, fb.x1[t]);
                    float yy2 = fminf(b.z, fb.y2[t]);
                    float xx2 = fminf(b.w, fb.x2[t]);
                    float inter = fmaxf(yy2 - yy1, 0.0f) * fmaxf(xx2 - xx1, 0.0f);
                    float iou = inter / (fb.ar[t] + ab - inter);
                    s = iou > NMS_T;
                }
                sup = (__ballot(s) != 0ULL);
            }
            if (!sup) {
                if (lane == 0) {
                    fb.y1[nk2] = b.x; fb.x1[nk2] = b.y;
                    fb.y2[nk2] = b.z; fb.x2[nk2] = b.w; fb.ar[nk2] = ab;
                }
                nk2++;
                if (nk2 == NPOST) break;
            }
        }
        for (int k = lane; k < NPOST; k += 64) {
            float4 o = make_float4(0.f, 0.f, 0.f, 0.f);
            if (k < nk2) o = make_float4(fb.y1[k], fb.x1[k], fb.y2[k], fb.x2[k]);
            out4[k] = o;
        }
    }
}

extern "C" void kernel_launch(void* const* d_in, const int* in_sizes, int n_in,
                              void* d_out, int out_size, void* d_ws, size_t ws_size,
                              hipStream_t stream) {
    const float4* loc    = (const float4*)d_in[0];
    const float*  score  = (const float*)d_in[1];
    const float4* anchor = (const float4*)d_in[2];
    const int*    ph     = (const int*)d_in[3];
    const int*    pw     = (const int*)d_in[4];
    int n = in_sizes[1];

    char* ws = (char*)d_ws;
    u64*      cand6  = (u64*)(ws + OFF_CAND6);
    u64*      candA  = (u64*)(ws + OFF_CANDA);
    float4*   roiA   = (float4*)(ws + OFF_ROIA);
    u64*      vsup   = (u64*)(ws + OFF_VSUP);
    unsigned* order6 = (unsigned*)(ws + OFF_ORDER6);
    float4*   roi6   = (float4*)(ws + OFF_ROI6);
    u64*      gmat   = (u64*)(ws + OFF_GMAT);
    unsigned* slots  = (unsigned*)(ws + OFF_SLOT);
    unsigned* cnts   = (unsigned*)(ws + OFF_CNT);
    float* out = (float*)d_out;

    k_hist    <<<dim3(NSLOT), dim3(256), 0, stream>>>(score, n, slots, cnts);
    k_compact <<<dim3(128),   dim3(256), 0, stream>>>(loc, score, anchor, ph, pw, n, slots,
                                                      candA, cand6, cnts);
    k_rankmat <<<dim3(8),     dim3(256), 0, stream>>>(loc, anchor, ph, pw, candA, cnts,
                                                      gmat, roiA, vsup);
    k_scan    <<<dim3(1),     dim3(256), 0, stream>>>(loc, anchor, ph, pw, n, cand6, cnts,
                                                      roiA, vsup, gmat, order6, roi6, out);
}

// Round 9
// 115.850 us; speedup vs baseline: 3.7494x; 1.0401x over previous
//
#include <hip/hip_runtime.h>
#include <stdint.h>

typedef unsigned long long u64;

#define NMS_T 0.7f
#define MINSZ 16.0f
#define NPRE 6000
#define NPOST 300
#define CA   512
#define CAPA 2048
#define CAP6 8192
#define NBIN 2048
#define NSLOT 32

// ---- workspace layout (bytes) ----
#define OFF_CAND6  0                          // CAP6*8  = 65536
#define OFF_CANDA  (OFF_CAND6 + CAP6*8)       // CAPA*8  = 16384
#define OFF_ROIA   (OFF_CANDA + CAPA*8)       // CA*16   = 8192
#define OFF_VSUP   (OFF_ROIA + CA*16)         // 64  (VALID-bit mask, 8 u64)
#define OFF_ORDER6 (OFF_VSUP + 64)            // NPRE*4  (fallback)
#define OFF_ROI6   (OFF_ORDER6 + NPRE*4)      // NPRE*16 (fallback)
#define OFF_GMAT   (OFF_ROI6 + NPRE*16)       // CA*8*8 word-major gmat[w*CA+row]
#define OFF_SLOT   (OFF_GMAT + CA*64)         // NSLOT*NBIN*4
#define OFF_CNT    (OFF_SLOT + NSLOT*NBIN*4)  // 32: [0]=cntA [1]=cnt6

__device__ __forceinline__ unsigned inv_key(float s) {
    unsigned u = __float_as_uint(s);
    unsigned k = (u & 0x80000000u) ? ~u : (u | 0x80000000u);
    return ~k;   // ascending inv == descending score
}

__device__ __forceinline__ float4 decode_box(const float4 a, const float4 l,
                                             float ih, float iw) {
    float h  = a.z - a.x;
    float w  = a.w - a.y;
    float cy = a.x + 0.5f * h;
    float cx = a.y + 0.5f * w;
    float ncy = l.x * h + cy;
    float ncx = l.y * w + cx;
    float nh  = expf(l.z) * h;
    float nw  = expf(l.w) * w;
    float y1 = fminf(fmaxf(ncy - 0.5f * nh, 0.0f), ih);
    float x1 = fminf(fmaxf(ncx - 0.5f * nw, 0.0f), iw);
    float y2 = fminf(fmaxf(ncy + 0.5f * nh, 0.0f), ih);
    float x2 = fminf(fmaxf(ncx + 0.5f * nw, 0.0f), iw);
    return make_float4(y1, x1, y2, x2);
}

__device__ __forceinline__ int sbin_of(float s) {
    int b = (int)(s * 2048.0f);
    b = b < 0 ? 0 : (b > 2047 ? 2047 : b);
    return 2047 - b;           // ascending = descending score
}

__device__ __forceinline__ u64 readlane64(u64 v, int lane) {
    unsigned lo = (unsigned)__builtin_amdgcn_readlane((int)(unsigned)v, lane);
    unsigned hi = (unsigned)__builtin_amdgcn_readlane((int)(unsigned)(v >> 32), lane);
    return ((u64)hi << 32) | (u64)lo;
}

// block-wide (256 threads) scan of 2048-bin histogram; bins containing ranks t0/t1
__device__ void scan2048(const unsigned* __restrict__ h, unsigned t0, unsigned t1,
                         unsigned* psum, unsigned* res, int base) {
    int t = threadIdx.x;
    unsigned vals[8];
    unsigned s = 0;
#pragma unroll
    for (int j = 0; j < 8; j++) { vals[j] = h[t * 8 + j]; s += vals[j]; }
    psum[t] = s;
    __syncthreads();
    for (int off = 1; off < 256; off <<= 1) {
        unsigned v = (t >= off) ? psum[t - off] : 0u;
        __syncthreads();
        psum[t] += v;
        __syncthreads();
    }
    unsigned run = (t == 0) ? 0u : psum[t - 1];
#pragma unroll
    for (int j = 0; j < 8; j++) {
        unsigned c = vals[j];
        if (run < t0 && run + c >= t0) { res[base + 0] = t * 8 + j; res[base + 1] = run; }
        if (t1 && run < t1 && run + c >= t1) { res[base + 2] = t * 8 + j; res[base + 3] = run; }
        run += c;
    }
    __syncthreads();
}

// ---- 1: score-only histogram; 8x float4 register-batched loads ----
__global__ void __launch_bounds__(256) k_hist(const float* __restrict__ score, int n,
                                              unsigned* __restrict__ slots,
                                              unsigned* __restrict__ cnts) {
    __shared__ unsigned lh[NBIN];
    for (int b = threadIdx.x; b < NBIN; b += 256) lh[b] = 0;
    if (blockIdx.x == 0 && threadIdx.x < 8) cnts[threadIdx.x] = 0;
    __syncthreads();
    int gtid = blockIdx.x * 256 + threadIdx.x;
    int T = gridDim.x * 256;
    int n4 = n >> 2;
    const float4* s4 = (const float4*)score;
    for (int idx0 = gtid; idx0 < n4; idx0 += T * 8) {
        float4 v[8]; int ok[8];
#pragma unroll
        for (int k = 0; k < 8; ++k) {
            int idx = idx0 + k * T;
            ok[k] = idx < n4;
            v[k] = ok[k] ? s4[idx] : make_float4(0.f, 0.f, 0.f, 0.f);
        }
#pragma unroll
        for (int k = 0; k < 8; ++k) if (ok[k]) {
            atomicAdd(&lh[sbin_of(v[k].x)], 1u);
            atomicAdd(&lh[sbin_of(v[k].y)], 1u);
            atomicAdd(&lh[sbin_of(v[k].z)], 1u);
            atomicAdd(&lh[sbin_of(v[k].w)], 1u);
        }
    }
    for (int i = (n4 << 2) + gtid; i < n; i += T) atomicAdd(&lh[sbin_of(score[i])], 1u);
    __syncthreads();
    for (int b = threadIdx.x; b < NBIN; b += 256)
        slots[blockIdx.x * NBIN + b] = lh[b];
}

// ---- 2: thresholds -> mask-count -> block prefix -> winner decode+write ----
__global__ void __launch_bounds__(256) k_compact(
        const float4* __restrict__ loc, const float* __restrict__ score,
        const float4* __restrict__ anchor, const int* __restrict__ ph,
        const int* __restrict__ pw, int n, const unsigned* __restrict__ slots,
        u64* __restrict__ candA, u64* __restrict__ cand6, unsigned* __restrict__ cnts) {
    __shared__ unsigned hsum[NBIN];
    __shared__ unsigned psum[256];
    __shared__ unsigned res[8];
    __shared__ unsigned sbase[2];
    int tid = threadIdx.x;
    for (int b = tid; b < NBIN; b += 256) {
        unsigned s = 0;
#pragma unroll 4
        for (int sl = 0; sl < NSLOT; ++sl) s += slots[sl * NBIN + b];
        hsum[b] = s;
    }
    __syncthreads();
    scan2048(hsum, CA, NPRE, psum, res, 0);   // res0 = bA, res2 = b6
    unsigned bA = res[0], b6 = res[2];
    float ih = (float)ph[0], iw = (float)pw[0];
    int gtid = blockIdx.x * 256 + tid;
    int T = gridDim.x * 256;
    int n4 = n >> 2;
    const float4* s4 = (const float4*)score;
    // phase 1: count (8x float4 batched)
    unsigned c6 = 0, cA = 0;
    for (int idx0 = gtid; idx0 < n4; idx0 += T * 8) {
        float4 v[8]; int ok[8];
#pragma unroll
        for (int k = 0; k < 8; ++k) {
            int idx = idx0 + k * T;
            ok[k] = idx < n4;
            v[k] = ok[k] ? s4[idx] : make_float4(0.f, 0.f, 0.f, 0.f);
        }
#pragma unroll
        for (int k = 0; k < 8; ++k) if (ok[k]) {
            unsigned h0 = (unsigned)sbin_of(v[k].x), h1 = (unsigned)sbin_of(v[k].y);
            unsigned h2 = (unsigned)sbin_of(v[k].z), h3 = (unsigned)sbin_of(v[k].w);
            c6 += (h0 <= b6) + (h1 <= b6) + (h2 <= b6) + (h3 <= b6);
            cA += (h0 <= bA) + (h1 <= bA) + (h2 <= bA) + (h3 <= bA);
        }
    }
    int ntail = n4 << 2;
    for (int i = ntail + gtid; i < n; i += T) {
        unsigned hb = (unsigned)sbin_of(score[i]);
        c6 += (hb <= b6);
        cA += (hb <= bA);
    }
    psum[tid] = (cA << 16) | c6;
    __syncthreads();
    for (int off = 1; off < 256; off <<= 1) {
        unsigned v = (tid >= off) ? psum[tid - off] : 0u;
        __syncthreads();
        psum[tid] += v;
        __syncthreads();
    }
    if (tid == 0) {
        unsigned tot = psum[255];
        sbase[0] = atomicAdd(&cnts[1], tot & 0xFFFFu);
        sbase[1] = atomicAdd(&cnts[0], tot >> 16);
    }
    __syncthreads();
    unsigned excl = (tid == 0) ? 0u : psum[tid - 1];
    unsigned pos6 = sbase[0] + (excl & 0xFFFFu);
    unsigned posA = sbase[1] + (excl >> 16);
    // phase 2: reload (L2-hot), decode winners (~6.5K total), write keys
    for (int idx0 = gtid; idx0 < n4; idx0 += T * 8) {
        float4 v[8]; int ok[8];
#pragma unroll
        for (int k = 0; k < 8; ++k) {
            int idx = idx0 + k * T;
            ok[k] = idx < n4;
            v[k] = ok[k] ? s4[idx] : make_float4(0.f, 0.f, 0.f, 0.f);
        }
#pragma unroll
        for (int k = 0; k < 8; ++k) if (ok[k]) {
            float sc[4] = {v[k].x, v[k].y, v[k].z, v[k].w};
            int ib = (idx0 + k * T) << 2;
#pragma unroll
            for (int c = 0; c < 4; ++c) {
                unsigned hb = (unsigned)sbin_of(sc[c]);
                if (hb <= b6) {
                    int i = ib + c;
                    float4 r = decode_box(anchor[i], loc[i], ih, iw);
                    bool valid = ((r.z - r.x) >= MINSZ) && ((r.w - r.y) >= MINSZ);
                    float ms = valid ? sc[c] : -__builtin_inff();
                    u64 key = ((u64)inv_key(ms) << 32) | (unsigned)i;
                    if (pos6 < CAP6) cand6[pos6] = key;
                    pos6++;
                    if (hb <= bA) {
                        if (posA < CAPA) candA[posA] = key;
                        posA++;
                    }
                }
            }
        }
    }
    for (int i = ntail + gtid; i < n; i += T) {
        float s = score[i];
        unsigned hb = (unsigned)sbin_of(s);
        if (hb <= b6) {
            float4 r = decode_box(anchor[i], loc[i], ih, iw);
            bool valid = ((r.z - r.x) >= MINSZ) && ((r.w - r.y) >= MINSZ);
            float ms = valid ? s : -__builtin_inff();
            u64 key = ((u64)inv_key(ms) << 32) | (unsigned)i;
            if (pos6 < CAP6) cand6[pos6] = key;
            pos6++;
            if (hb <= bA) {
                if (posA < CAPA) candA[posA] = key;
                posA++;
            }
        }
    }
}

// register-blocked exact rank + decode of top-CA; j-loop batched 16-wide to break
// the per-iteration LDS latency chain (broadcast reads, independent)
template <int KB>
__device__ __forceinline__ void rank_block(const u64* lk2, unsigned MP,
                                           const float4* anchor, const float4* loc,
                                           float ih, float iw,
                                           float4* sroi, float* sarea, unsigned* svalid) {
    u64 kc[KB]; int rr[KB];
#pragma unroll
    for (int k = 0; k < KB; ++k) {
        unsigned c = threadIdx.x + k * 256u;
        kc[k] = (c < MP) ? lk2[c] : ~0ULL;
        rr[k] = 0;
    }
    unsigned j = 0;
    for (; j + 16 <= MP; j += 16) {
        u64 kj[16];
#pragma unroll
        for (int t = 0; t < 16; ++t) kj[t] = lk2[j + t];
#pragma unroll
        for (int t = 0; t < 16; ++t) {
#pragma unroll
            for (int k = 0; k < KB; ++k) rr[k] += (kj[t] < kc[k]) ? 1 : 0;
        }
    }
    for (; j < MP; ++j) {
        u64 kj = lk2[j];
#pragma unroll
        for (int k = 0; k < KB; ++k) rr[k] += (kj < kc[k]) ? 1 : 0;
    }
#pragma unroll
    for (int k = 0; k < KB; ++k) {
        unsigned c = threadIdx.x + k * 256u;
        if (c < MP && rr[k] < CA) {
            unsigned idx = (unsigned)kc[k];
            float4 b = decode_box(anchor[idx], loc[idx], ih, iw);
            sroi[rr[k]] = b;
            sarea[rr[k]] = (b.z - b.x) * (b.w - b.y);
            if (((b.z - b.x) >= MINSZ) && ((b.w - b.y) >= MINSZ))
                atomicOr(&svalid[rr[k] >> 5], 1u << (rr[k] & 31));
        }
    }
}

// ---- 3: 8 parallel blocks: prune -> rank -> decode -> matrix slice ----
__global__ void __launch_bounds__(256) k_rankmat(
        const float4* __restrict__ loc, const float4* __restrict__ anchor,
        const int* __restrict__ ph, const int* __restrict__ pw,
        const u64* __restrict__ candA, const unsigned* __restrict__ cnts,
        u64* __restrict__ gmat, float4* __restrict__ roiA, u64* __restrict__ vsup_g) {
    __shared__ u64 lk[CAPA];
    __shared__ u64 lk2[CAPA];
    __shared__ unsigned shist[NBIN];
    __shared__ float4 sroi[CA];
    __shared__ float sarea[CA];
    __shared__ unsigned svalid[CA / 32];
    __shared__ unsigned psum[256];
    __shared__ unsigned res2[8];
    __shared__ unsigned sInvLo, sMP;
    int tid = threadIdx.x;
    unsigned cntA = cnts[0];
    if (cntA > CAPA) return;                      // flag path handled in k_scan
    unsigned MA = cntA;
    float ih = (float)ph[0], iw = (float)pw[0];

    if (tid == 0) { sInvLo = 0xFFFFFFFFu; sMP = 0; res2[0] = NBIN - 1; }
    for (int b = tid; b < NBIN; b += 256) shist[b] = 0;
    for (int r = tid; r < CA; r += 256) { sroi[r] = make_float4(0.f,0.f,0.f,0.f); sarea[r] = 0.f; }
    if (tid < CA / 32) svalid[tid] = 0;
    __syncthreads();
    // load keys + wave-reduced min (4 LDS atomics total, not MA)
    unsigned mymin = 0xFFFFFFFFu;
    for (unsigned i = tid; i < MA; i += 256) {
        u64 k = candA[i];
        lk[i] = k;
        unsigned hi = (unsigned)(k >> 32);
        mymin = mymin < hi ? mymin : hi;
    }
#pragma unroll
    for (int off = 32; off; off >>= 1) {
        unsigned o = (unsigned)__shfl_down((int)mymin, off, 64);
        mymin = mymin < o ? mymin : o;
    }
    if ((tid & 63) == 0) atomicMin(&sInvLo, mymin);
    __syncthreads();
    unsigned invLo = sInvLo;
    for (unsigned i = tid; i < MA; i += 256) {
        unsigned d = ((unsigned)(lk[i] >> 32) - invLo) >> 3;
        atomicAdd(&shist[d > 2047u ? 2047u : d], 1u);
    }
    __syncthreads();
    scan2048(shist, CA, 0, psum, res2, 0);        // res2[0] = sub-bin threshold
    unsigned sbT = res2[0];
    // ballot-compact winners into lk2 (1 atomic per wave per pass; order irrelevant)
    unsigned MAr = (MA + 255u) & ~255u;
    for (unsigned i = tid; i < MAr; i += 256) {
        bool win = false;
        u64 key = 0;
        if (i < MA) {
            key = lk[i];
            unsigned d = ((unsigned)(key >> 32) - invLo) >> 3;
            win = ((d > 2047u ? 2047u : d) <= sbT);
        }
        u64 mask = __ballot(win);
        unsigned base = 0;
        if ((tid & 63) == 0 && mask) base = atomicAdd(&sMP, (unsigned)__popcll(mask));
        base = (unsigned)__builtin_amdgcn_readfirstlane((int)base);
        if (win) {
            unsigned pos = base + (unsigned)__popcll(mask & ((1ull << (tid & 63)) - 1ull));
            lk2[pos] = key;
        }
    }
    __syncthreads();
    unsigned MP = sMP;                             // >= min(512, MA), typically ~520
    if (MP <= 1024) rank_block<4>(lk2, MP, anchor, loc, ih, iw, sroi, sarea, svalid);
    else            rank_block<8>(lk2, MP, anchor, loc, ih, iw, sroi, sarea, svalid);
    __syncthreads();
    int w = blockIdx.x;
    int j0 = w * 64;
#pragma unroll
    for (int rrr = 0; rrr < 2; ++rrr) {
        int row = tid + rrr * 256;
        u64 bits = 0;
        if (j0 + 63 > row) {
            float4 b = sroi[row];
            float ab = sarea[row];
#pragma unroll 4
            for (int jj = 0; jj < 64; ++jj) {
                int j = j0 + jj;
                if (j > row) {
                    float4 c = sroi[j];
                    float yy1 = fmaxf(b.x, c.x);
                    float xx1 = fmaxf(b.y, c.y);
                    float yy2 = fminf(b.z, c.z);
                    float xx2 = fminf(b.w, c.w);
                    float inter = fmaxf(yy2 - yy1, 0.0f) * fmaxf(xx2 - xx1, 0.0f);
                    float iou = inter / (ab + sarea[j] - inter);  // ref op order
                    if (iou > NMS_T) bits |= (1ULL << jj);
                }
            }
        }
        gmat[w * CA + row] = bits;
    }
    if (blockIdx.x == 0) {
        for (int r = tid; r < CA; r += 256) roiA[r] = sroi[r];
        if (tid < 8) vsup_g[tid] = ((u64)svalid[2 * tid + 1] << 32) | (u64)svalid[2 * tid];
    }
}

struct SmFb {
    u64   lk[CAP6];                                // 64 KB
    float y1[NPOST], x1[NPOST], y2[NPOST], x2[NPOST], ar[NPOST];
};

// ---- 4: single block: group-serial scan, O(1) per kept + deferred butterfly fold ----
__global__ void __launch_bounds__(256) k_scan(
        const float4* __restrict__ loc, const float4* __restrict__ anchor,
        const int* __restrict__ ph, const int* __restrict__ pw, int n,
        const u64* __restrict__ cand6, const unsigned* __restrict__ cnts,
        const float4* __restrict__ roiA, const u64* __restrict__ vsup_g,
        const u64* __restrict__ gmat,
        unsigned* __restrict__ order6, float4* __restrict__ roi6,
        float* __restrict__ out) {
    __shared__ SmFb fb;
    __shared__ u64 skm[8];
    __shared__ int snk, sflag;
    int tid = threadIdx.x;
    unsigned cntA = cnts[0], cnt6 = cnts[1];
    bool mainValid = (cntA <= CAPA);
    int Ceff = (int)(cntA < (unsigned)CA ? cntA : (unsigned)CA);
    float ih = (float)ph[0], iw = (float)pw[0];

    if (tid < 64 && mainValid) {
        u64 supfut[8], curM[8], nxtM[8], kmask[8];
#pragma unroll
        for (int w = 0; w < 8; ++w) { supfut[w] = ~vsup_g[w]; kmask[w] = 0ull; }
#pragma unroll
        for (int w = 0; w < 8; ++w) curM[w] = gmat[w * CA + tid];
        int nk = 0;
        bool done = false;
#pragma unroll
        for (int g = 0; g < 8; ++g) {
            if (g < 7) {
#pragma unroll
                for (int w = 0; w < 8; ++w) nxtM[w] = gmat[w * CA + 64 * (g + 1) + tid];
            }
            int base = 64 * g;
            if (!done && base < Ceff) {
                u64 bound = (Ceff - base >= 64) ? ~0ull : ((1ull << (Ceff - base)) - 1ull);
                u64 live = ~supfut[g] & bound;
                u64 km = 0;
                while (live) {
                    int b = (int)__builtin_ctzll(live);
                    km |= (1ull << b);
                    ++nk;
                    if (nk == NPOST) { done = true; break; }
                    u64 row = readlane64(curM[g], b);   // word g of kept row: 2 readlanes
                    live &= ~(row | (1ull << b));
                }
                kmask[g] = km;
                if (!done && g < 7) {                   // deferred cross-group fold
                    bool mk = ((km >> tid) & 1ull) != 0ull;
                    u64 c[8];
#pragma unroll
                    for (int w = g + 1; w < 8; ++w) c[w] = mk ? curM[w] : 0ull;
#pragma unroll
                    for (int off = 1; off < 64; off <<= 1) {
#pragma unroll
                        for (int w = g + 1; w < 8; ++w) c[w] |= __shfl_xor(c[w], off, 64);
                    }
#pragma unroll
                    for (int w = g + 1; w < 8; ++w) supfut[w] |= c[w];
                }
            }
#pragma unroll
            for (int w = 0; w < 8; ++w) curM[w] = nxtM[w];
        }
        if (tid == 0) {
            snk = nk;
            sflag = (nk < NPOST && cnt6 > (unsigned)Ceff) ? 1 : 0;
            skm[0] = kmask[0]; skm[1] = kmask[1]; skm[2] = kmask[2]; skm[3] = kmask[3];
            skm[4] = kmask[4]; skm[5] = kmask[5]; skm[6] = kmask[6]; skm[7] = kmask[7];
        }
    }
    if (tid == 0 && !mainValid) {
        snk = 0; sflag = 1;
        skm[0]=0; skm[1]=0; skm[2]=0; skm[3]=0; skm[4]=0; skm[5]=0; skm[6]=0; skm[7]=0;
    }
    __syncthreads();
    int nk = snk, flag = sflag;
    float4* out4 = (float4*)out;
    if (!flag) {
        int basepc[8];
        {
            int run = 0;
#pragma unroll
            for (int g = 0; g < 8; ++g) { basepc[g] = run; run += __popcll(skm[g]); }
        }
        int wv = tid >> 6, j = tid & 63;
#pragma unroll
        for (int gg = 0; gg < 2; ++gg) {
            int g = wv * 2 + gg;
            u64 km = skm[g];
            if ((km >> j) & 1ull) {
                int rank = basepc[g] + __popcll(km & ((1ull << j) - 1ull));
                if (rank < NPOST) out4[rank] = roiA[64 * g + j];
            }
        }
        for (int k = nk + tid; k < NPOST; k += 256) out4[k] = make_float4(0.f,0.f,0.f,0.f);
        return;
    }
    // ---------- exact fallback (gated; never taken on sane data) ----------
    unsigned M = cnt6 < (unsigned)CAP6 ? cnt6 : (unsigned)CAP6;
    for (unsigned i = tid; i < CAP6; i += 256) fb.lk[i] = (i < M) ? cand6[i] : ~0ULL;
    for (int r = tid; r < NPRE; r += 256) order6[r] = 0xFFFFFFFFu;
    __syncthreads();
    for (unsigned c = tid; c < M; c += 256) {
        u64 key = fb.lk[c];
        int rank = 0;
        for (unsigned j = 0; j < M; ++j) rank += (fb.lk[j] < key) ? 1 : 0;
        if (rank < NPRE) order6[rank] = (unsigned)key;
    }
    __syncthreads();
    for (int r = tid; r < NPRE; r += 256) {
        unsigned idx = order6[r];
        float4 b = make_float4(0.f, 0.f, 0.f, 0.f);
        if (idx < (unsigned)n) b = decode_box(anchor[idx], loc[idx], ih, iw);
        roi6[r] = b;
    }
    __syncthreads();
    if (tid < 64) {
        int lane = tid;
        int nk2 = 0;
        for (int i = 0; i < NPRE; i++) {
            float4 b = roi6[i];
            float hs = b.z - b.x, wd = b.w - b.y;
            if (!(hs >= MINSZ && wd >= MINSZ)) continue;
            float ab = hs * wd;
            bool sup = false;
            for (int base = 0; base < nk2 && !sup; base += 64) {
                int t = base + lane;
                bool s = false;
                if (t < nk2) {
                    float yy1 = fmaxf(b.x, fb.y1[t]);
                    float xx1 = fmaxf(b.y, fb.x1[t]);
                    float yy2 = fminf(b.z, fb.y2[t]);
                    float xx2 = fminf(b.w, fb.x2[t]);
                    float inter = fmaxf(yy2 - yy1, 0.0f) * fmaxf(xx2 - xx1, 0.0f);
                    float iou = inter / (fb.ar[t] + ab - inter);
                    s = iou > NMS_T;
                }
                sup = (__ballot(s) != 0ULL);
            }
            if (!sup) {
                if (lane == 0) {
                    fb.y1[nk2] = b.x; fb.x1[nk2] = b.y;
                    fb.y2[nk2] = b.z; fb.x2[nk2] = b.w; fb.ar[nk2] = ab;
                }
                nk2++;
                if (nk2 == NPOST) break;
            }
        }
        for (int k = lane; k < NPOST; k += 64) {
            float4 o = make_float4(0.f, 0.f, 0.f, 0.f);
            if (k < nk2) o = make_float4(fb.y1[k], fb.x1[k], fb.y2[k], fb.x2[k]);
            out4[k] = o;
        }
    }
}

extern "C" void kernel_launch(void* const* d_in, const int* in_sizes, int n_in,
                              void* d_out, int out_size, void* d_ws, size_t ws_size,
                              hipStream_t stream) {
    const float4* loc    = (const float4*)d_in[0];
    const float*  score  = (const float*)d_in[1];
    const float4* anchor = (const float4*)d_in[2];
    const int*    ph     = (const int*)d_in[3];
    const int*    pw     = (const int*)d_in[4];
    int n = in_sizes[1];

    char* ws = (char*)d_ws;
    u64*      cand6  = (u64*)(ws + OFF_CAND6);
    u64*      candA  = (u64*)(ws + OFF_CANDA);
    float4*   roiA   = (float4*)(ws + OFF_ROIA);
    u64*      vsup   = (u64*)(ws + OFF_VSUP);
    unsigned* order6 = (unsigned*)(ws + OFF_ORDER6);
    float4*   roi6   = (float4*)(ws + OFF_ROI6);
    u64*      gmat   = (u64*)(ws + OFF_GMAT);
    unsigned* slots  = (unsigned*)(ws + OFF_SLOT);
    unsigned* cnts   = (unsigned*)(ws + OFF_CNT);
    float* out = (float*)d_out;

    k_hist    <<<dim3(NSLOT), dim3(256), 0, stream>>>(score, n, slots, cnts);
    k_compact <<<dim3(128),   dim3(256), 0, stream>>>(loc, score, anchor, ph, pw, n, slots,
                                                      candA, cand6, cnts);
    k_rankmat <<<dim3(8),     dim3(256), 0, stream>>>(loc, anchor, ph, pw, candA, cnts,
                                                      gmat, roiA, vsup);
    k_scan    <<<dim3(1),     dim3(256), 0, stream>>>(loc, anchor, ph, pw, n, cand6, cnts,
                                                      roiA, vsup, gmat, order6, roi6, out);
}